// Round 15
// baseline (2007.894 us; speedup 1.0000x reference)
//
#include <hip/hip_runtime.h>
#include <cstdint>
#include <cstddef>

constexpr int Bg = 64;     // graphs
constexpr int Nn = 1024;   // nodes per graph
constexpr int Kk = 10;     // kNN neighbors
constexpr int BN = Bg * Nn;
#define SLOPE 0.01f

typedef __attribute__((ext_vector_type(8))) short s16x8;
typedef __attribute__((ext_vector_type(4))) float f32x4;

__device__ __forceinline__ float lrelu(float v) { return v >= 0.f ? v : SLOPE * v; }

__device__ __forceinline__ unsigned encf(float f) {
  unsigned u = __float_as_uint(f);
  return (u & 0x80000000u) ? ~u : (u | 0x80000000u);
}
__device__ __forceinline__ float decf(unsigned e) {
  unsigned u = (e & 0x80000000u) ? (e & 0x7fffffffu) : ~e;
  return __uint_as_float(u);
}
__device__ __forceinline__ unsigned short f2bf(float f) {
  unsigned u = __float_as_uint(f);
  return (unsigned short)((u + 0x7FFFu + ((u >> 16) & 1u)) >> 16);
}
__device__ __forceinline__ float bf2f(unsigned short h) {
  return __uint_as_float(((unsigned)h) << 16);
}

__device__ __forceinline__ f32x4 mfma16(s16x8 a, s16x8 b, f32x4 c) {
  return __builtin_amdgcn_mfma_f32_16x16x32_bf16(a, b, c, 0, 0, 0);
}

__global__ __launch_bounds__(256) void pooled_init(unsigned* __restrict__ p) {
  p[blockIdx.x * 256 + threadIdx.x] = 0u;
}

// ---------------- build xx = [tq, x, pos] + fused sq ----------------
__global__ __launch_bounds__(256) void build_xx(const float* __restrict__ x,
                                                const float* __restrict__ pos,
                                                const float* __restrict__ tq,
                                                float* __restrict__ xx,
                                                float* __restrict__ sqn, int rowoff) {
  int n = blockIdx.x * 256 + threadIdx.x;
  int g = rowoff + n;
  float v0 = tq[g], v1 = x[g];
  float v2 = pos[g * 3 + 0], v3 = pos[g * 3 + 1], v4 = pos[g * 3 + 2];
  xx[n * 5 + 0] = v0;
  xx[n * 5 + 1] = v1;
  xx[n * 5 + 2] = v2;
  xx[n * 5 + 3] = v3;
  xx[n * 5 + 4] = v4;
  float s0 = v0 * v0, s1 = v1 * v1, s2 = v2 * v2, s3 = v3 * v3, s4 = v4 * v4;
  sqn[n] = ((s0 + s4) + s2) + (s1 + s3);
}

// ---------------- weight prep: W[K][512] f32 -> WH/WL [512][K] bf16 ----------------
template <int K>
__global__ __launch_bounds__(256) void wprep(const float* __restrict__ W,
                                             short* __restrict__ WH,
                                             short* __restrict__ WL) {
  int idx = blockIdx.x * 256 + threadIdx.x;
  int k = idx >> 9, n = idx & 511;
  float v = W[idx];
  unsigned short h = f2bf(v);
  unsigned short lo = f2bf(v - bf2f(h));
  WH[(size_t)n * K + k] = (short)h;
  WL[(size_t)n * K + k] = (short)lo;
}

// ---------------- U = h @ (Wt - Wb), V = h @ Wb  (conv1 only, F=5) ----------------
template <int F>
__global__ __launch_bounds__(256) void uv_kernel(const float* __restrict__ h,
                                                 const float* __restrict__ W,
                                                 float* __restrict__ U,
                                                 float* __restrict__ V) {
  __shared__ float Ws[2 * F * 64];
  __shared__ float hs[16 * F];
  const int t = threadIdx.x;
  const int n0 = blockIdx.x * 16;
  for (int l = t; l < 2 * F * 64; l += 256) Ws[l] = W[l];
  for (int l = t; l < 16 * F; l += 256) hs[l] = h[(size_t)n0 * F + l];
  __syncthreads();
  for (int l = t; l < F * 64; l += 256) Ws[l] = Ws[l] - Ws[F * 64 + l];
  __syncthreads();
  const int o = t & 63;
  #pragma unroll
  for (int g4 = 0; g4 < 16; g4 += 4) {
    const int g = g4 + (t >> 6);
    float u = 0.f, v = 0.f;
    for (int f = 0; f < F; ++f) {
      float hv = hs[g * F + f];
      u += hv * Ws[f * 64 + o];
      v += hv * Ws[F * 64 + f * 64 + o];
    }
    U[(size_t)(n0 + g) * 64 + o] = u;
    V[(size_t)(n0 + g) * 64 + o] = v;
  }
}

// Branchless sorted top-10 (d,j) ladder, monotone-compare form (round-13 proven).
#define LADDER_STATE                                                                     \
  float bd0 = INFINITY, bd1 = INFINITY, bd2 = INFINITY, bd3 = INFINITY, bd4 = INFINITY,  \
        bd5 = INFINITY, bd6 = INFINITY, bd7 = INFINITY, bd8 = INFINITY, bd9 = INFINITY;  \
  int bj0 = 0x7fffffff, bj1 = 0x7fffffff, bj2 = 0x7fffffff, bj3 = 0x7fffffff,            \
      bj4 = 0x7fffffff, bj5 = 0x7fffffff, bj6 = 0x7fffffff, bj7 = 0x7fffffff,            \
      bj8 = 0x7fffffff, bj9 = 0x7fffffff;

#define LADDER_INS                                                                        \
  auto ins = [&](float kd, int kj) {                                                      \
    bool m0 = kd < bd0; bool m1 = kd < bd1; bool m2 = kd < bd2; bool m3 = kd < bd3;       \
    bool m4 = kd < bd4; bool m5 = kd < bd5; bool m6 = kd < bd6; bool m7 = kd < bd7;       \
    bool m8 = kd < bd8; bool m9 = kd < bd9;                                               \
    bd9 = m8 ? bd8 : (m9 ? kd : bd9); bj9 = m8 ? bj8 : (m9 ? kj : bj9);                   \
    bd8 = m7 ? bd7 : (m8 ? kd : bd8); bj8 = m7 ? bj7 : (m8 ? kj : bj8);                   \
    bd7 = m6 ? bd6 : (m7 ? kd : bd7); bj7 = m6 ? bj6 : (m7 ? kj : bj7);                   \
    bd6 = m5 ? bd5 : (m6 ? kd : bd6); bj6 = m5 ? bj5 : (m6 ? kj : bj6);                   \
    bd5 = m4 ? bd4 : (m5 ? kd : bd5); bj5 = m4 ? bj4 : (m5 ? kj : bj5);                   \
    bd4 = m3 ? bd3 : (m4 ? kd : bd4); bj4 = m3 ? bj3 : (m4 ? kj : bj4);                   \
    bd3 = m2 ? bd2 : (m3 ? kd : bd3); bj3 = m2 ? bj2 : (m3 ? kj : bj3);                   \
    bd2 = m1 ? bd1 : (m2 ? kd : bd2); bj2 = m1 ? bj1 : (m2 ? kj : bj2);                   \
    bd1 = m0 ? bd0 : (m1 ? kd : bd1); bj1 = m0 ? bj0 : (m1 ? kj : bj1);                   \
    bd0 = m0 ? kd : bd0;              bj0 = m0 ? kj : bj0;                                \
  };

#define FMA16(av, bv)                                                        \
  do {                                                                       \
    acc[0][0] += av.x * bv.x; acc[0][1] += av.x * bv.y;                      \
    acc[0][2] += av.x * bv.z; acc[0][3] += av.x * bv.w;                      \
    acc[1][0] += av.y * bv.x; acc[1][1] += av.y * bv.y;                      \
    acc[1][2] += av.y * bv.z; acc[1][3] += av.y * bv.w;                      \
    acc[2][0] += av.z * bv.x; acc[2][1] += av.z * bv.y;                      \
    acc[2][2] += av.z * bv.z; acc[2][3] += av.z * bv.w;                      \
    acc[3][0] += av.w * bv.x; acc[3][1] += av.w * bv.y;                      \
    acc[3][2] += av.w * bv.z; acc[3][3] += av.w * bv.w;                      \
  } while (0)

// ---------------- kNN (F=5, fp32 VALU path; round-13 proven) ----------------
template <int F>
__global__ __launch_bounds__(256) void knn_kernel(const float* __restrict__ h,
                                                  const float* __restrict__ sqn,
                                                  int* __restrict__ idxout) {
  constexpr int IPB = 64;
  constexpr int TJ = 64;
  constexpr int LDA = 68;
  constexpr int LDD = 65;
  constexpr int LDM = 41;
  constexpr int UNI = (IPB * LDM * 2 > TJ * LDA) ? IPB * LDM * 2 : TJ * LDA;
  __shared__ float As[F][LDA];
  __shared__ float uni[UNI];
  __shared__ float sqt[TJ];
  float* Bs = uni;
  float* D  = uni;
  float* md = uni;
  int*   mi = (int*)(uni + IPB * LDM);

  const int b = blockIdx.y;
  const int i0 = blockIdx.x * IPB;
  const int t = threadIdx.x;
  const int tx = t & 15, ty = t >> 4;
  const int gbase = b * Nn;
  const int r = t & 63;
  const int s = t >> 6;

  for (int l = t; l < IPB * F; l += 256) {
    int row = l / F, f = l % F;
    As[f][row] = h[(size_t)(gbase + i0 + row) * F + f];
  }

  LADDER_STATE
  LADDER_INS

  for (int jt = 0; jt < Nn; jt += TJ) {
    __syncthreads();
    for (int l = t; l < TJ * F; l += 256) {
      int row = l / F, f = l % F;
      Bs[f * LDA + row] = h[(size_t)(gbase + jt + row) * F + f];
    }
    if (t < TJ) sqt[t] = sqn[gbase + jt + t];
    __syncthreads();

    float acc[4][4] = {{0.f, 0.f, 0.f, 0.f}, {0.f, 0.f, 0.f, 0.f},
                       {0.f, 0.f, 0.f, 0.f}, {0.f, 0.f, 0.f, 0.f}};
    #pragma unroll
    for (int f = 0; f < F; ++f) {
      float4 av = *(const float4*)&As[f][ty * 4];
      float4 bv = *(const float4*)(Bs + f * LDA + tx * 4);
      FMA16(av, bv);
    }
    __syncthreads();

    float4 sj = *(const float4*)&sqt[tx * 4];
    #pragma unroll
    for (int ii = 0; ii < 4; ++ii) {
      float* dr = D + (ty * 4 + ii) * LDD + tx * 4;
      dr[0] = sj.x - 2.f * acc[ii][0];
      dr[1] = sj.y - 2.f * acc[ii][1];
      dr[2] = sj.z - 2.f * acc[ii][2];
      dr[3] = sj.w - 2.f * acc[ii][3];
    }
    __syncthreads();

    {
      const float* drow = D + r * LDD + s * 16;
      float dv[16];
      #pragma unroll
      for (int qq = 0; qq < 16; ++qq) dv[qq] = drow[qq];
      #pragma unroll
      for (int qq = 0; qq < 16; ++qq) ins(dv[qq], jt + s * 16 + qq);
    }
  }

  __syncthreads();
  {
    float* rd = md + r * LDM + s * 10;
    int*   ri = mi + r * LDM + s * 10;
    rd[0] = bd0; rd[1] = bd1; rd[2] = bd2; rd[3] = bd3; rd[4] = bd4;
    rd[5] = bd5; rd[6] = bd6; rd[7] = bd7; rd[8] = bd8; rd[9] = bd9;
    ri[0] = bj0; ri[1] = bj1; ri[2] = bj2; ri[3] = bj3; ri[4] = bj4;
    ri[5] = bj5; ri[6] = bj6; ri[7] = bj7; ri[8] = bj8; ri[9] = bj9;
  }
  __syncthreads();
  if (s == 0) {
    float* rd = md + r * LDM;
    int*   ri = mi + r * LDM;
    #pragma unroll 1
    for (int q = 0; q < Kk; ++q) {
      float best = INFINITY;
      int besti = 0x7fffffff, bslot = 0;
      #pragma unroll 1
      for (int e = 0; e < 40; ++e) {
        float d = rd[e];
        int ix = ri[e];
        bool g = (d < best) || (d == best && ix < besti);
        if (g) { best = d; besti = ix; bslot = e; }
      }
      rd[bslot] = INFINITY;
      idxout[(size_t)(gbase + i0 + r) * Kk + q] = besti;
    }
  }
}

// ---------------- FUSED: kNN(F=64, swapped-operand MFMA) + agg (+ next uv + sq) ----------------
// knn phase identical to round-14 knn64_mfma; idx stays in LDS; agg/uv phases are the
// round-12/13 aggF bodies verbatim (bit-identical math). sqn in/out are DISTINCT buffers.
template <bool FUSE>
__global__ __launch_bounds__(256) void knnagg(const short* __restrict__ hHin,
                                              const short* __restrict__ hLin,
                                              const float* __restrict__ sqn,
                                              const float* __restrict__ U,
                                              const float* __restrict__ V,
                                              const float* __restrict__ bias,
                                              short* __restrict__ hHout,
                                              short* __restrict__ hLout,
                                              const float* __restrict__ W,   // [128][64]
                                              float* __restrict__ Uo,
                                              float* __restrict__ Vo,
                                              float* __restrict__ sqno) {
  constexpr int LDB = 72;
  constexpr int LDM = 41;
  // pool: knn B-tiles (2 bufs x H/L = 36864 B) | merge md/mi (20992 B) | Ws (32768 B)
  __shared__ __align__(16) char pool[2 * 2 * 64 * LDB * 2];
  __shared__ float sqt[2][64];
  __shared__ float hs[FUSE ? 64 : 1][68];
  __shared__ float prt[FUSE ? 64 : 1][4];
  __shared__ int idx_s[64][10];
  float* md = (float*)pool;
  int*   mi = (int*)(md + 64 * LDM);
  float* Ws = (float*)pool;

  const int b = blockIdx.y;
  const int i0 = blockIdx.x * 64;
  const int t = threadIdx.x;
  const int gbase = b * Nn;

  // ================= kNN phase (round-14 proven) =================
  {
    const int w = t >> 6, l = t & 63;
    const int rl = l & 15, kb = l >> 4;
    auto Bp = [&](int buf, int plane) -> short* {
      return (short*)pool + ((size_t)buf * 2 + plane) * 64 * LDB;
    };

    s16x8 aH0, aH1, aL0, aL1;
    {
      const size_t ar = (size_t)(gbase + i0 + w * 16 + rl) * 64;
      aH0 = *(const s16x8*)&hHin[ar + kb * 8];
      aH1 = *(const s16x8*)&hHin[ar + 32 + kb * 8];
      aL0 = *(const s16x8*)&hLin[ar + kb * 8];
      aL1 = *(const s16x8*)&hLin[ar + 32 + kb * 8];
    }

    LADDER_STATE
    LADDER_INS

    uint4 pH0, pH1, pL0, pL1;
    {
      const size_t rb = (size_t)(gbase + l) * 64;
      pH0 = *(const uint4*)&hHin[rb + w * 8];
      pH1 = *(const uint4*)&hHin[rb + (w + 4) * 8];
      pL0 = *(const uint4*)&hLin[rb + w * 8];
      pL1 = *(const uint4*)&hLin[rb + (w + 4) * 8];
    }
    *(uint4*)&Bp(0, 0)[l * LDB + w * 8]       = pH0;
    *(uint4*)&Bp(0, 0)[l * LDB + (w + 4) * 8] = pH1;
    *(uint4*)&Bp(0, 1)[l * LDB + w * 8]       = pL0;
    *(uint4*)&Bp(0, 1)[l * LDB + (w + 4) * 8] = pL1;
    if (t < 64) sqt[0][t] = sqn[gbase + t];
    {
      const size_t rb = (size_t)(gbase + 64 + l) * 64;
      pH0 = *(const uint4*)&hHin[rb + w * 8];
      pH1 = *(const uint4*)&hHin[rb + (w + 4) * 8];
      pL0 = *(const uint4*)&hLin[rb + w * 8];
      pL1 = *(const uint4*)&hLin[rb + (w + 4) * 8];
    }
    __syncthreads();

    int cur = 0;
    for (int jt = 0; jt < Nn; jt += 64) {
      if (jt + 64 < Nn) {
        short* BH1 = Bp(cur ^ 1, 0);
        short* BL1 = Bp(cur ^ 1, 1);
        *(uint4*)&BH1[l * LDB + w * 8]       = pH0;
        *(uint4*)&BH1[l * LDB + (w + 4) * 8] = pH1;
        *(uint4*)&BL1[l * LDB + w * 8]       = pL0;
        *(uint4*)&BL1[l * LDB + (w + 4) * 8] = pL1;
        if (t < 64) sqt[cur ^ 1][t] = sqn[gbase + jt + 64 + t];
        if (jt + 128 < Nn) {
          const size_t rb = (size_t)(gbase + jt + 128 + l) * 64;
          pH0 = *(const uint4*)&hHin[rb + w * 8];
          pH1 = *(const uint4*)&hHin[rb + (w + 4) * 8];
          pL0 = *(const uint4*)&hLin[rb + w * 8];
          pL1 = *(const uint4*)&hLin[rb + (w + 4) * 8];
        }
      }

      const short* BH = Bp(cur, 0);
      const short* BL = Bp(cur, 1);
      f32x4 dists[4];
      #pragma unroll
      for (int cg = 0; cg < 4; ++cg) {
        const int co = (cg * 16 + rl) * LDB;
        s16x8 bh0 = *(const s16x8*)&BH[co + kb * 8];
        s16x8 bh1 = *(const s16x8*)&BH[co + 32 + kb * 8];
        s16x8 bl0 = *(const s16x8*)&BL[co + kb * 8];
        s16x8 bl1 = *(const s16x8*)&BL[co + 32 + kb * 8];
        f32x4 a = (f32x4){0.f, 0.f, 0.f, 0.f};
        a = mfma16(bh0, aH0, a); a = mfma16(bl0, aH0, a);
        a = mfma16(bh0, aL0, a); a = mfma16(bl0, aL0, a);
        a = mfma16(bh1, aH1, a); a = mfma16(bl1, aH1, a);
        a = mfma16(bh1, aL1, a); a = mfma16(bl1, aL1, a);
        dists[cg] = a;
      }
      #pragma unroll
      for (int cg = 0; cg < 4; ++cg) {
        float4 sj = *(const float4*)&sqt[cur][cg * 16 + kb * 4];
        int jb = jt + cg * 16 + kb * 4;
        ins(sj.x - 2.f * dists[cg][0], jb + 0);
        ins(sj.y - 2.f * dists[cg][1], jb + 1);
        ins(sj.z - 2.f * dists[cg][2], jb + 2);
        ins(sj.w - 2.f * dists[cg][3], jb + 3);
      }
      __syncthreads();
      cur ^= 1;
    }

    // merge 4 sorted-10s per row -> idx_s
    {
      const int row = w * 16 + rl;
      float* rd = md + row * LDM + kb * 10;
      int*   ri = mi + row * LDM + kb * 10;
      rd[0] = bd0; rd[1] = bd1; rd[2] = bd2; rd[3] = bd3; rd[4] = bd4;
      rd[5] = bd5; rd[6] = bd6; rd[7] = bd7; rd[8] = bd8; rd[9] = bd9;
      ri[0] = bj0; ri[1] = bj1; ri[2] = bj2; ri[3] = bj3; ri[4] = bj4;
      ri[5] = bj5; ri[6] = bj6; ri[7] = bj7; ri[8] = bj8; ri[9] = bj9;
    }
    __syncthreads();
    if (t < 64) {
      float* rd = md + t * LDM;
      int*   ri = mi + t * LDM;
      #pragma unroll 1
      for (int q = 0; q < Kk; ++q) {
        float best = INFINITY;
        int besti = 0x7fffffff, bslot = 0;
        #pragma unroll 1
        for (int e = 0; e < 40; ++e) {
          float d = rd[e];
          int ix = ri[e];
          bool g = (d < best) || (d == best && ix < besti);
          if (g) { best = d; besti = ix; bslot = e; }
        }
        rd[bslot] = INFINITY;
        idx_s[t][q] = besti;
      }
    }
    __syncthreads();   // idx_s ready; md/mi dead -> Ws may reuse pool
  }

  // ================= agg (+uv+sq) phase (round-12/13 aggF verbatim) =================
  {
    const int r = t >> 2, s = t & 3, o0 = s * 16;
    const int n = gbase + i0 + r;

    if constexpr (FUSE) {
      for (int l = t; l < 2 * 64 * 64; l += 256) Ws[l] = W[l];
    }

    float4 u[4], bb[4], acc[4];
    #pragma unroll
    for (int q = 0; q < 4; ++q) {
      u[q] = *(const float4*)&U[(size_t)n * 64 + o0 + q * 4];
      bb[q] = *(const float4*)&bias[o0 + q * 4];
      acc[q] = make_float4(0.f, 0.f, 0.f, 0.f);
    }
    #pragma unroll
    for (int k = 0; k < Kk; ++k) {
      int j = gbase + idx_s[r][k];
      #pragma unroll
      for (int q = 0; q < 4; ++q) {
        float4 v = *(const float4*)&V[(size_t)j * 64 + o0 + q * 4];
        acc[q].x += lrelu(u[q].x + v.x + bb[q].x);
        acc[q].y += lrelu(u[q].y + v.y + bb[q].y);
        acc[q].z += lrelu(u[q].z + v.z + bb[q].z);
        acc[q].w += lrelu(u[q].w + v.w + bb[q].w);
      }
    }
    #pragma unroll
    for (int q = 0; q < 4; ++q) {
      ushort4 hv, lv;
      hv.x = f2bf(acc[q].x); lv.x = f2bf(acc[q].x - bf2f(hv.x));
      hv.y = f2bf(acc[q].y); lv.y = f2bf(acc[q].y - bf2f(hv.y));
      hv.z = f2bf(acc[q].z); lv.z = f2bf(acc[q].z - bf2f(hv.z));
      hv.w = f2bf(acc[q].w); lv.w = f2bf(acc[q].w - bf2f(hv.w));
      *(ushort4*)&hHout[(size_t)n * 64 + o0 + q * 4] = hv;
      *(ushort4*)&hLout[(size_t)n * 64 + o0 + q * 4] = lv;
    }
    if constexpr (!FUSE) return;

    #pragma unroll
    for (int q = 0; q < 4; ++q) *(float4*)&hs[r][o0 + q * 4] = acc[q];
    {
      float p = 0.f;
      #pragma unroll
      for (int q = 0; q < 4; ++q) {
        p += acc[q].x * acc[q].x;
        p += acc[q].y * acc[q].y;
        p += acc[q].z * acc[q].z;
        p += acc[q].w * acc[q].w;
      }
      prt[r][s] = p;
    }
    __syncthreads();
    for (int l = t; l < 64 * 64; l += 256) Ws[l] = Ws[l] - Ws[64 * 64 + l];
    if (s == 0) sqno[n] = ((prt[r][0] + prt[r][1]) + prt[r][2]) + prt[r][3];
    __syncthreads();

    const int o = t & 63;
    for (int g4 = 0; g4 < 64; g4 += 4) {
      const int g = g4 + (t >> 6);
      float uu = 0.f, vv = 0.f;
      for (int f = 0; f < 64; ++f) {
        float hv = hs[g][f];
        uu += hv * Ws[f * 64 + o];
        vv += hv * Ws[64 * 64 + f * 64 + o];
      }
      Uo[(size_t)(gbase + i0 + g) * 64 + o] = uu;
      Vo[(size_t)(gbase + i0 + g) * 64 + o] = vv;
    }
  }
}

// ---------------- standalone fused agg (+ next uv + sq) — conv1 only ----------------
template <bool FUSE>
__global__ __launch_bounds__(256) void aggF_kernel(const float* __restrict__ U,
                                                   const float* __restrict__ V,
                                                   const int* __restrict__ idx,
                                                   const float* __restrict__ bias,
                                                   short* __restrict__ hH,
                                                   short* __restrict__ hL,
                                                   const float* __restrict__ W,
                                                   float* __restrict__ Uo,
                                                   float* __restrict__ Vo,
                                                   float* __restrict__ sqno) {
  __shared__ float Ws[FUSE ? 2 * 64 * 64 : 1];
  __shared__ float hs[FUSE ? 64 : 1][68];
  __shared__ float prt[FUSE ? 64 : 1][4];
  const int t = threadIdx.x;
  const int n0 = blockIdx.x * 64;
  const int r = t >> 2, s = t & 3, o0 = s * 16;
  const int n = n0 + r;
  const int gb = n & ~(Nn - 1);

  if constexpr (FUSE) {
    for (int l = t; l < 2 * 64 * 64; l += 256) Ws[l] = W[l];
  }

  float4 u[4], bb[4], acc[4];
  #pragma unroll
  for (int q = 0; q < 4; ++q) {
    u[q] = *(const float4*)&U[(size_t)n * 64 + o0 + q * 4];
    bb[q] = *(const float4*)&bias[o0 + q * 4];
    acc[q] = make_float4(0.f, 0.f, 0.f, 0.f);
  }
  #pragma unroll
  for (int k = 0; k < Kk; ++k) {
    int j = gb + idx[n * Kk + k];
    #pragma unroll
    for (int q = 0; q < 4; ++q) {
      float4 v = *(const float4*)&V[(size_t)j * 64 + o0 + q * 4];
      acc[q].x += lrelu(u[q].x + v.x + bb[q].x);
      acc[q].y += lrelu(u[q].y + v.y + bb[q].y);
      acc[q].z += lrelu(u[q].z + v.z + bb[q].z);
      acc[q].w += lrelu(u[q].w + v.w + bb[q].w);
    }
  }
  #pragma unroll
  for (int q = 0; q < 4; ++q) {
    ushort4 hv, lv;
    hv.x = f2bf(acc[q].x); lv.x = f2bf(acc[q].x - bf2f(hv.x));
    hv.y = f2bf(acc[q].y); lv.y = f2bf(acc[q].y - bf2f(hv.y));
    hv.z = f2bf(acc[q].z); lv.z = f2bf(acc[q].z - bf2f(hv.z));
    hv.w = f2bf(acc[q].w); lv.w = f2bf(acc[q].w - bf2f(hv.w));
    *(ushort4*)&hH[(size_t)n * 64 + o0 + q * 4] = hv;
    *(ushort4*)&hL[(size_t)n * 64 + o0 + q * 4] = lv;
  }
  if constexpr (!FUSE) return;

  #pragma unroll
  for (int q = 0; q < 4; ++q) *(float4*)&hs[r][o0 + q * 4] = acc[q];
  {
    float p = 0.f;
    #pragma unroll
    for (int q = 0; q < 4; ++q) {
      p += acc[q].x * acc[q].x;
      p += acc[q].y * acc[q].y;
      p += acc[q].z * acc[q].z;
      p += acc[q].w * acc[q].w;
    }
    prt[r][s] = p;
  }
  __syncthreads();
  for (int l = t; l < 64 * 64; l += 256) Ws[l] = Ws[l] - Ws[64 * 64 + l];
  if (s == 0) sqno[n] = ((prt[r][0] + prt[r][1]) + prt[r][2]) + prt[r][3];
  __syncthreads();

  const int o = t & 63;
  for (int g4 = 0; g4 < 64; g4 += 4) {
    const int g = g4 + (t >> 6);
    float uu = 0.f, vv = 0.f;
    for (int f = 0; f < 64; ++f) {
      float hv = hs[g][f];
      uu += hv * Ws[f * 64 + o];
      vv += hv * Ws[64 * 64 + f * 64 + o];
    }
    Uo[(size_t)(n0 + g) * 64 + o] = uu;
    Vo[(size_t)(n0 + g) * 64 + o] = vv;
  }
}

// ---------------- MFMA bf16x2 (hi/lo, 3-term) GEMM, 128x128 tile ----------------
// Global loads hoisted above the first barrier (latency overlaps barrier wait).
template <int MODE>
__global__ __launch_bounds__(256) void mfma_gemm(const short* __restrict__ AH,
                                                 const short* __restrict__ AL,
                                                 const short* __restrict__ BH,
                                                 const short* __restrict__ BL,
                                                 const float* __restrict__ bias,
                                                 short* __restrict__ outH,
                                                 short* __restrict__ outL,
                                                 unsigned* __restrict__ pooled,
                                                 int Msl, int zc, int g0) {
  constexpr int Kdim = (MODE == 0) ? 384 : 512;
  __shared__ short AHs[128][40], ALs[128][40], BHs[128][40], BLs[128][40];
  __shared__ float red[8][132];
  const int t = threadIdx.x;
  const int m0 = blockIdx.y * 128, n0 = blockIdx.x * 128;
  const int w = t >> 6, l = t & 63;
  const int q = w >> 1, p = w & 1, rl = l & 15, kb = l >> 4;
  const int srow = t >> 1, sc = (t & 1) * 16;

  f32x4 acc[4][4];
  #pragma unroll
  for (int m = 0; m < 4; ++m)
    #pragma unroll
    for (int n = 0; n < 4; ++n) acc[m][n] = (f32x4){0.f, 0.f, 0.f, 0.f};

  for (int k0 = 0; k0 < Kdim; k0 += 32) {
    size_t aoff, boff;
    if constexpr (MODE == 0)
      aoff = ((size_t)(k0 >> 6) * Msl + zc + m0 + srow) * 64 + (k0 & 63) + sc;
    else
      aoff = (size_t)(m0 + srow) * 512 + k0 + sc;
    boff = (size_t)(n0 + srow) * Kdim + k0 + sc;
    // hoist: issue all 8 global loads before the barrier
    uint4 ga0 = *(const uint4*)(AH + aoff);
    uint4 ga1 = *(const uint4*)(AH + aoff + 8);
    uint4 gl0 = *(const uint4*)(AL + aoff);
    uint4 gl1 = *(const uint4*)(AL + aoff + 8);
    uint4 gb0 = *(const uint4*)(BH + boff);
    uint4 gb1 = *(const uint4*)(BH + boff + 8);
    uint4 gc0 = *(const uint4*)(BL + boff);
    uint4 gc1 = *(const uint4*)(BL + boff + 8);
    __syncthreads();
    *(uint4*)&AHs[srow][sc]     = ga0;
    *(uint4*)&AHs[srow][sc + 8] = ga1;
    *(uint4*)&ALs[srow][sc]     = gl0;
    *(uint4*)&ALs[srow][sc + 8] = gl1;
    *(uint4*)&BHs[srow][sc]     = gb0;
    *(uint4*)&BHs[srow][sc + 8] = gb1;
    *(uint4*)&BLs[srow][sc]     = gc0;
    *(uint4*)&BLs[srow][sc + 8] = gc1;
    __syncthreads();

    s16x8 aH[4], aL[4], bH[4], bL[4];
    #pragma unroll
    for (int m = 0; m < 4; ++m) {
      aH[m] = *(const s16x8*)&AHs[q * 64 + m * 16 + rl][kb * 8];
      aL[m] = *(const s16x8*)&ALs[q * 64 + m * 16 + rl][kb * 8];
    }
    #pragma unroll
    for (int n = 0; n < 4; ++n) {
      bH[n] = *(const s16x8*)&BHs[p * 64 + n * 16 + rl][kb * 8];
      bL[n] = *(const s16x8*)&BLs[p * 64 + n * 16 + rl][kb * 8];
    }
    #pragma unroll
    for (int m = 0; m < 4; ++m)
      #pragma unroll
      for (int n = 0; n < 4; ++n) {
        acc[m][n] = mfma16(aH[m], bH[n], acc[m][n]);
        acc[m][n] = mfma16(aH[m], bL[n], acc[m][n]);
        acc[m][n] = mfma16(aL[m], bH[n], acc[m][n]);
      }
  }

  if constexpr (MODE == 0) {
    #pragma unroll
    for (int n = 0; n < 4; ++n) {
      const int col = n0 + p * 64 + n * 16 + rl;
      const float bv = bias[col];
      #pragma unroll
      for (int m = 0; m < 4; ++m) {
        #pragma unroll
        for (int rr = 0; rr < 4; ++rr) {
          int row = m0 + q * 64 + m * 16 + kb * 4 + rr;
          float v = lrelu(acc[m][n][rr] + bv);
          unsigned short hv = f2bf(v);
          unsigned short lv = f2bf(v - bf2f(hv));
          outH[(size_t)row * 512 + col] = (short)hv;
          outL[(size_t)row * 512 + col] = (short)lv;
        }
      }
    }
  } else {
    #pragma unroll
    for (int n = 0; n < 4; ++n) {
      float cm = acc[0][n][0];
      #pragma unroll
      for (int m = 0; m < 4; ++m)
        #pragma unroll
        for (int rr = 0; rr < 4; ++rr) cm = fmaxf(cm, acc[m][n][rr]);
      red[q * 4 + kb][p * 64 + n * 16 + rl] = cm;
    }
    __syncthreads();
    if (t < 128) {
      float m = red[0][t];
      #pragma unroll
      for (int rr = 1; rr < 8; ++rr) m = fmaxf(m, red[rr][t]);
      m += bias[n0 + t];
      int g = g0 + ((zc + m0) >> 10);
      atomicMax(&pooled[(size_t)g * 512 + n0 + t], encf(m));
    }
  }
}

// ---------------- head ----------------
__global__ __launch_bounds__(256) void head_kernel(const unsigned* __restrict__ pooled,
                                                   const float* __restrict__ Wm1,
                                                   const float* __restrict__ bm1,
                                                   const float* __restrict__ Wm2,
                                                   const float* __restrict__ bm2,
                                                   float* __restrict__ out) {
  __shared__ float ps[512];
  __shared__ float hs[256];
  int b = blockIdx.x;
  int t = threadIdx.x;
  for (int l = t; l < 512; l += 256) ps[l] = decf(pooled[(size_t)b * 512 + l]);
  __syncthreads();
  float acc = bm1[t];
  for (int f = 0; f < 512; ++f) acc += ps[f] * Wm1[f * 256 + t];
  hs[t] = lrelu(acc);
  __syncthreads();
  if (t < 3) {
    float y = bm2[t];
    for (int f = 0; f < 256; ++f) y += hs[f] * Wm2[f * 3 + t];
    out[b * 3 + t] = y;
  }
}

static inline size_t al256(size_t v) { return (v + 255) & ~(size_t)255; }

extern "C" void kernel_launch(void* const* d_in, const int* in_sizes, int n_in,
                              void* d_out, int out_size, void* d_ws, size_t ws_size,
                              hipStream_t stream) {
  (void)in_sizes; (void)n_in; (void)out_size;
  const float* x    = (const float*)d_in[0];
  const float* pos  = (const float*)d_in[1];
  const float* tq   = (const float*)d_in[2];
  // d_in[3] = batch (uniform & sorted; unused)
  const float* W1   = (const float*)d_in[4];
  const float* b1   = (const float*)d_in[5];
  const float* W2   = (const float*)d_in[6];
  const float* b2   = (const float*)d_in[7];
  const float* Wl1a = (const float*)d_in[8];
  const float* bl1a = (const float*)d_in[9];
  const float* Wl1b = (const float*)d_in[10];
  const float* bl1b = (const float*)d_in[11];
  const float* Wm1  = (const float*)d_in[12];
  const float* bm1  = (const float*)d_in[13];
  const float* Wm2  = (const float*)d_in[14];
  const float* bm2  = (const float*)d_in[15];
  float* out = (float*)d_out;

  // ---- pick largest graph-chunk G whose workspace fits ----
  auto calc = [&](int G, size_t& hHB, size_t& uvB, size_t& uvzB) -> size_t {
    size_t M = (size_t)G * Nn;
    hHB = al256(M * 384 * 2);                 // hH (and hL): 6 slots [M][64] bf16
    uvB = al256(M * 64 * 4);                  // each of Ua,Va,Ub,Vb
    size_t Mz = M < 16384 ? M : 16384;
    size_t zB = 2 * al256(Mz * 512 * 2);      // zH+zL (alias U/V region)
    uvzB = (4 * uvB > zB) ? 4 * uvB : zB;
    size_t convS = al256(M * 5 * 4) + 2 * al256(M * 4) + al256(M * Kk * 4);
    size_t wB = 2 * al256((size_t)512 * 384 * 2) + 2 * al256((size_t)512 * 512 * 2);
    return 2 * hHB + uvzB + convS + al256((size_t)Bg * 512 * 4) + wB + 1024;
  };
  int G = 64;
  size_t hHB = 0, uvB = 0, uvzB = 0;
  while (G > 1 && calc(G, hHB, uvB, uvzB) > ws_size) G >>= 1;
  calc(G, hHB, uvB, uvzB);
  const int M = G * Nn;
  const int Mz = M < 16384 ? M : 16384;

  char* w = (char*)d_ws;
  short* hH = (short*)w;
  short* hL = (short*)(w + hHB);
  char*  uvz = w + 2 * hHB;
  float* Ua = (float*)uvz;
  float* Va = (float*)(uvz + uvB);
  float* Ub = (float*)(uvz + 2 * uvB);
  float* Vb = (float*)(uvz + 3 * uvB);
  short* zH = (short*)uvz;                                  // MLP aliases U/V region
  short* zL = (short*)(uvz + al256((size_t)Mz * 512 * 2));
  char*  conv = uvz + uvzB;
  float* xx   = (float*)conv;
  float* sqnA = (float*)(conv + al256((size_t)M * 5 * 4));
  float* sqnB = (float*)((char*)sqnA + al256((size_t)M * 4));
  int*   idx  = (int*)((char*)sqnB + al256((size_t)M * 4));
  unsigned* pooled = (unsigned*)((char*)idx + al256((size_t)M * Kk * 4));
  short* WHa = (short*)((char*)pooled + al256((size_t)Bg * 512 * 4));
  short* WLa = WHa + (size_t)512 * 384;
  short* WHb = (short*)((char*)WHa + 2 * al256((size_t)512 * 384 * 2));
  short* WLb = WHb + (size_t)512 * 512;

  wprep<384><<<(384 * 512) / 256, 256, 0, stream>>>(Wl1a, WHa, WLa);
  wprep<512><<<(512 * 512) / 256, 256, 0, stream>>>(Wl1b, WHb, WLb);
  pooled_init<<<(Bg * 512) / 256, 256, 0, stream>>>(pooled);

  for (int g0 = 0; g0 < Bg; g0 += G) {
    build_xx<<<M / 256, 256, 0, stream>>>(x, pos, tq, xx, sqnA, g0 * Nn);

    // conv1 (F=5, W1) -> slot 0; fused uv(conv2)+sq (standalone, idx via global)
    uv_kernel<5><<<M / 16, 256, 0, stream>>>(xx, W1, Ua, Va);
    knn_kernel<5><<<dim3(Nn / 64, G), 256, 0, stream>>>(xx, sqnA, idx);
    aggF_kernel<true><<<M / 64, 256, 0, stream>>>(Ua, Va, idx, b1, hH, hL,
                                                  W2, Ub, Vb, sqnB);

    // conv2..6 -> slots 1..5 (fused kNN+agg; sqn ping-pong)
    float *Ui = Ub, *Vi = Vb, *Uo = Ua, *Vo = Va;
    float *sqI = sqnB, *sqO = sqnA;
    for (int c = 1; c < 6; ++c) {
      const short* hHin = hH + (size_t)(c - 1) * M * 64;
      const short* hLin = hL + (size_t)(c - 1) * M * 64;
      short* hHout = hH + (size_t)c * M * 64;
      short* hLout = hL + (size_t)c * M * 64;
      if (c < 5) {
        knnagg<true><<<dim3(Nn / 64, G), 256, 0, stream>>>(hHin, hLin, sqI,
                                                           Ui, Vi, b2, hHout, hLout,
                                                           W2, Uo, Vo, sqO);
        { float* tp = Ui; Ui = Uo; Uo = tp; tp = Vi; Vi = Vo; Vo = tp;
          tp = sqI; sqI = sqO; sqO = tp; }
      } else {
        knnagg<false><<<dim3(Nn / 64, G), 256, 0, stream>>>(hHin, hLin, sqI,
                                                            Ui, Vi, b2, hHout, hLout,
                                                            nullptr, nullptr, nullptr, nullptr);
      }
    }

    // MLP over this chunk's rows, z-chunked
    for (int zc = 0; zc < M; zc += Mz) {
      mfma_gemm<0><<<dim3(4, Mz / 128), 256, 0, stream>>>(hH, hL, WHa, WLa, bl1a,
                                                          zH, zL, nullptr, M, zc, 0);
      mfma_gemm<1><<<dim3(4, Mz / 128), 256, 0, stream>>>(zH, zL, WHb, WLb, bl1b,
                                                          nullptr, nullptr, pooled, Mz, zc, g0);
    }
  }

  head_kernel<<<Bg, 256, 0, stream>>>(pooled, Wm1, bm1, Wm2, bm2, out);
}

// Round 16
// 1537.377 us; speedup vs baseline: 1.3061x; 1.3061x over previous
//
#include <hip/hip_runtime.h>
#include <cstdint>
#include <cstddef>

constexpr int Bg = 64;     // graphs
constexpr int Nn = 1024;   // nodes per graph
constexpr int Kk = 10;     // kNN neighbors
constexpr int BN = Bg * Nn;
#define SLOPE 0.01f

typedef __attribute__((ext_vector_type(8))) short s16x8;
typedef __attribute__((ext_vector_type(4))) float f32x4;

__device__ __forceinline__ float lrelu(float v) { return v >= 0.f ? v : SLOPE * v; }

__device__ __forceinline__ unsigned encf(float f) {
  unsigned u = __float_as_uint(f);
  return (u & 0x80000000u) ? ~u : (u | 0x80000000u);
}
__device__ __forceinline__ float decf(unsigned e) {
  unsigned u = (e & 0x80000000u) ? (e & 0x7fffffffu) : ~e;
  return __uint_as_float(u);
}
__device__ __forceinline__ unsigned short f2bf(float f) {
  unsigned u = __float_as_uint(f);
  return (unsigned short)((u + 0x7FFFu + ((u >> 16) & 1u)) >> 16);
}
__device__ __forceinline__ float bf2f(unsigned short h) {
  return __uint_as_float(((unsigned)h) << 16);
}

__device__ __forceinline__ f32x4 mfma16(s16x8 a, s16x8 b, f32x4 c) {
  return __builtin_amdgcn_mfma_f32_16x16x32_bf16(a, b, c, 0, 0, 0);
}

__global__ __launch_bounds__(256) void pooled_init(unsigned* __restrict__ p) {
  p[blockIdx.x * 256 + threadIdx.x] = 0u;
}

// ---------------- build xx = [tq, x, pos] + fused sq (exact shfl-tree order) ----------------
__global__ __launch_bounds__(256) void build_xx(const float* __restrict__ x,
                                                const float* __restrict__ pos,
                                                const float* __restrict__ tq,
                                                float* __restrict__ xx,
                                                float* __restrict__ sqn, int rowoff) {
  int n = blockIdx.x * 256 + threadIdx.x;
  int g = rowoff + n;
  float v0 = tq[g], v1 = x[g];
  float v2 = pos[g * 3 + 0], v3 = pos[g * 3 + 1], v4 = pos[g * 3 + 2];
  xx[n * 5 + 0] = v0;
  xx[n * 5 + 1] = v1;
  xx[n * 5 + 2] = v2;
  xx[n * 5 + 3] = v3;
  xx[n * 5 + 4] = v4;
  float s0 = v0 * v0, s1 = v1 * v1, s2 = v2 * v2, s3 = v3 * v3, s4 = v4 * v4;
  sqn[n] = ((s0 + s4) + s2) + (s1 + s3);   // == sq_kernel's 64-lane shfl tree for F=5
}

// ---------------- weight prep: W[K][512] f32 -> WH/WL [512][K] bf16 ----------------
template <int K>
__global__ __launch_bounds__(256) void wprep(const float* __restrict__ W,
                                             short* __restrict__ WH,
                                             short* __restrict__ WL) {
  int idx = blockIdx.x * 256 + threadIdx.x;
  int k = idx >> 9, n = idx & 511;
  float v = W[idx];
  unsigned short h = f2bf(v);
  unsigned short lo = f2bf(v - bf2f(h));
  WH[(size_t)n * K + k] = (short)h;
  WL[(size_t)n * K + k] = (short)lo;
}

// ---------------- U = h @ (Wt - Wb), V = h @ Wb  (conv1 only, F=5) ----------------
template <int F>
__global__ __launch_bounds__(256) void uv_kernel(const float* __restrict__ h,
                                                 const float* __restrict__ W,  // [2F][64]
                                                 float* __restrict__ U,
                                                 float* __restrict__ V) {
  __shared__ float Ws[2 * F * 64];
  __shared__ float hs[16 * F];
  const int t = threadIdx.x;
  const int n0 = blockIdx.x * 16;
  for (int l = t; l < 2 * F * 64; l += 256) Ws[l] = W[l];
  for (int l = t; l < 16 * F; l += 256) hs[l] = h[(size_t)n0 * F + l];
  __syncthreads();
  for (int l = t; l < F * 64; l += 256) Ws[l] = Ws[l] - Ws[F * 64 + l];
  __syncthreads();
  const int o = t & 63;
  #pragma unroll
  for (int g4 = 0; g4 < 16; g4 += 4) {
    const int g = g4 + (t >> 6);
    float u = 0.f, v = 0.f;
    for (int f = 0; f < F; ++f) {
      float hv = hs[g * F + f];
      u += hv * Ws[f * 64 + o];
      v += hv * Ws[F * 64 + f * 64 + o];
    }
    U[(size_t)(n0 + g) * 64 + o] = u;
    V[(size_t)(n0 + g) * 64 + o] = v;
  }
}

// Branchless sorted top-10 (d,j) ladder, monotone-compare form (round-13 proven).
#define LADDER_STATE                                                                     \
  float bd0 = INFINITY, bd1 = INFINITY, bd2 = INFINITY, bd3 = INFINITY, bd4 = INFINITY,  \
        bd5 = INFINITY, bd6 = INFINITY, bd7 = INFINITY, bd8 = INFINITY, bd9 = INFINITY;  \
  int bj0 = 0x7fffffff, bj1 = 0x7fffffff, bj2 = 0x7fffffff, bj3 = 0x7fffffff,            \
      bj4 = 0x7fffffff, bj5 = 0x7fffffff, bj6 = 0x7fffffff, bj7 = 0x7fffffff,            \
      bj8 = 0x7fffffff, bj9 = 0x7fffffff;

#define LADDER_INS                                                                        \
  auto ins = [&](float kd, int kj) {                                                      \
    bool m0 = kd < bd0; bool m1 = kd < bd1; bool m2 = kd < bd2; bool m3 = kd < bd3;       \
    bool m4 = kd < bd4; bool m5 = kd < bd5; bool m6 = kd < bd6; bool m7 = kd < bd7;       \
    bool m8 = kd < bd8; bool m9 = kd < bd9;                                               \
    bd9 = m8 ? bd8 : (m9 ? kd : bd9); bj9 = m8 ? bj8 : (m9 ? kj : bj9);                   \
    bd8 = m7 ? bd7 : (m8 ? kd : bd8); bj8 = m7 ? bj7 : (m8 ? kj : bj8);                   \
    bd7 = m6 ? bd6 : (m7 ? kd : bd7); bj7 = m6 ? bj6 : (m7 ? kj : bj7);                   \
    bd6 = m5 ? bd5 : (m6 ? kd : bd6); bj6 = m5 ? bj5 : (m6 ? kj : bj6);                   \
    bd5 = m4 ? bd4 : (m5 ? kd : bd5); bj5 = m4 ? bj4 : (m5 ? kj : bj5);                   \
    bd4 = m3 ? bd3 : (m4 ? kd : bd4); bj4 = m3 ? bj3 : (m4 ? kj : bj4);                   \
    bd3 = m2 ? bd2 : (m3 ? kd : bd3); bj3 = m2 ? bj2 : (m3 ? kj : bj3);                   \
    bd2 = m1 ? bd1 : (m2 ? kd : bd2); bj2 = m1 ? bj1 : (m2 ? kj : bj2);                   \
    bd1 = m0 ? bd0 : (m1 ? kd : bd1); bj1 = m0 ? bj0 : (m1 ? kj : bj1);                   \
    bd0 = m0 ? kd : bd0;              bj0 = m0 ? kj : bj0;                                \
  };

#define FMA16(av, bv)                                                        \
  do {                                                                       \
    acc[0][0] += av.x * bv.x; acc[0][1] += av.x * bv.y;                      \
    acc[0][2] += av.x * bv.z; acc[0][3] += av.x * bv.w;                      \
    acc[1][0] += av.y * bv.x; acc[1][1] += av.y * bv.y;                      \
    acc[1][2] += av.y * bv.z; acc[1][3] += av.y * bv.w;                      \
    acc[2][0] += av.z * bv.x; acc[2][1] += av.z * bv.y;                      \
    acc[2][2] += av.z * bv.z; acc[2][3] += av.z * bv.w;                      \
    acc[3][0] += av.w * bv.x; acc[3][1] += av.w * bv.y;                      \
    acc[3][2] += av.w * bv.z; acc[3][3] += av.w * bv.w;                      \
  } while (0)

// ---------------- kNN (F=5, fp32 VALU path; round-13 proven) ----------------
template <int F>
__global__ __launch_bounds__(256) void knn_kernel(const float* __restrict__ h,
                                                  const float* __restrict__ sqn,
                                                  int* __restrict__ idxout) {
  constexpr int IPB = 64;
  constexpr int TJ = 64;
  constexpr int LDA = 68;
  constexpr int LDD = 65;
  constexpr int LDM = 41;
  constexpr int UNI = (IPB * LDM * 2 > TJ * LDA) ? IPB * LDM * 2 : TJ * LDA;
  __shared__ float As[F][LDA];
  __shared__ float uni[UNI];
  __shared__ float sqt[TJ];
  float* Bs = uni;
  float* D  = uni;
  float* md = uni;
  int*   mi = (int*)(uni + IPB * LDM);

  const int b = blockIdx.y;
  const int i0 = blockIdx.x * IPB;
  const int t = threadIdx.x;
  const int tx = t & 15, ty = t >> 4;
  const int gbase = b * Nn;
  const int r = t & 63;
  const int s = t >> 6;

  for (int l = t; l < IPB * F; l += 256) {
    int row = l / F, f = l % F;
    As[f][row] = h[(size_t)(gbase + i0 + row) * F + f];
  }

  LADDER_STATE
  LADDER_INS

  for (int jt = 0; jt < Nn; jt += TJ) {
    __syncthreads();
    for (int l = t; l < TJ * F; l += 256) {
      int row = l / F, f = l % F;
      Bs[f * LDA + row] = h[(size_t)(gbase + jt + row) * F + f];
    }
    if (t < TJ) sqt[t] = sqn[gbase + jt + t];
    __syncthreads();

    float acc[4][4] = {{0.f, 0.f, 0.f, 0.f}, {0.f, 0.f, 0.f, 0.f},
                       {0.f, 0.f, 0.f, 0.f}, {0.f, 0.f, 0.f, 0.f}};
    #pragma unroll
    for (int f = 0; f < F; ++f) {
      float4 av = *(const float4*)&As[f][ty * 4];
      float4 bv = *(const float4*)(Bs + f * LDA + tx * 4);
      FMA16(av, bv);
    }
    __syncthreads();

    float4 sj = *(const float4*)&sqt[tx * 4];
    #pragma unroll
    for (int ii = 0; ii < 4; ++ii) {
      float* dr = D + (ty * 4 + ii) * LDD + tx * 4;
      dr[0] = sj.x - 2.f * acc[ii][0];
      dr[1] = sj.y - 2.f * acc[ii][1];
      dr[2] = sj.z - 2.f * acc[ii][2];
      dr[3] = sj.w - 2.f * acc[ii][3];
    }
    __syncthreads();

    {
      const float* drow = D + r * LDD + s * 16;
      float dv[16];
      #pragma unroll
      for (int qq = 0; qq < 16; ++qq) dv[qq] = drow[qq];
      #pragma unroll
      for (int qq = 0; qq < 16; ++qq) ins(dv[qq], jt + s * 16 + qq);
    }
  }

  __syncthreads();
  {
    float* rd = md + r * LDM + s * 10;
    int*   ri = mi + r * LDM + s * 10;
    rd[0] = bd0; rd[1] = bd1; rd[2] = bd2; rd[3] = bd3; rd[4] = bd4;
    rd[5] = bd5; rd[6] = bd6; rd[7] = bd7; rd[8] = bd8; rd[9] = bd9;
    ri[0] = bj0; ri[1] = bj1; ri[2] = bj2; ri[3] = bj3; ri[4] = bj4;
    ri[5] = bj5; ri[6] = bj6; ri[7] = bj7; ri[8] = bj8; ri[9] = bj9;
  }
  __syncthreads();
  if (s == 0) {
    float* rd = md + r * LDM;
    int*   ri = mi + r * LDM;
    #pragma unroll 1
    for (int q = 0; q < Kk; ++q) {
      float best = INFINITY;
      int besti = 0x7fffffff, bslot = 0;
      #pragma unroll 1
      for (int e = 0; e < 40; ++e) {
        float d = rd[e];
        int ix = ri[e];
        bool g = (d < best) || (d == best && ix < besti);
        if (g) { best = d; besti = ix; bslot = e; }
      }
      rd[bslot] = INFINITY;
      idxout[(size_t)(gbase + i0 + r) * Kk + q] = besti;
    }
  }
}

// ---------------- kNN (F=64) v3: swapped-operand MFMA, in-register distances ----------------
// (round-14 proven: 153 us, VGPR 52, bit-identical distances via commutated mfma)
__global__ __launch_bounds__(256) void knn64_mfma(const short* __restrict__ hH,
                                                  const short* __restrict__ hL,
                                                  const float* __restrict__ sqn,
                                                  int* __restrict__ idxout) {
  constexpr int LDB = 72;   // shorts per row (144B, 16B-aligned)
  constexpr int LDM = 41;
  __shared__ __align__(16) short Bbuf[2][2][64 * LDB];  // [buf][H/L] = 36864 B
  __shared__ float sqt[2][64];
  float* md = (float*)&Bbuf[0][0][0];          // merge aliases dead B buffers at end
  int*   mi = (int*)(md + 64 * LDM);

  const int b = blockIdx.y;
  const int i0 = blockIdx.x * 64;
  const int t = threadIdx.x;
  const int w = t >> 6, l = t & 63;
  const int rl = l & 15, kb = l >> 4;
  const int gbase = b * Nn;

  // i-row fragments (used as MFMA *B* operand): wave w owns i = i0 + w*16 + rl
  s16x8 aH0, aH1, aL0, aL1;
  {
    const size_t ar = (size_t)(gbase + i0 + w * 16 + rl) * 64;
    aH0 = *(const s16x8*)&hH[ar + kb * 8];
    aH1 = *(const s16x8*)&hH[ar + 32 + kb * 8];
    aL0 = *(const s16x8*)&hL[ar + kb * 8];
    aL1 = *(const s16x8*)&hL[ar + 32 + kb * 8];
  }

  LADDER_STATE
  LADDER_INS

  // prefetch tile 0 -> regs, stage into buf 0, prefetch tile 1 -> regs
  uint4 pH0, pH1, pL0, pL1;
  {
    const size_t rb = (size_t)(gbase + l) * 64;
    pH0 = *(const uint4*)&hH[rb + w * 8];
    pH1 = *(const uint4*)&hH[rb + (w + 4) * 8];
    pL0 = *(const uint4*)&hL[rb + w * 8];
    pL1 = *(const uint4*)&hL[rb + (w + 4) * 8];
  }
  *(uint4*)&Bbuf[0][0][l * LDB + w * 8]       = pH0;
  *(uint4*)&Bbuf[0][0][l * LDB + (w + 4) * 8] = pH1;
  *(uint4*)&Bbuf[0][1][l * LDB + w * 8]       = pL0;
  *(uint4*)&Bbuf[0][1][l * LDB + (w + 4) * 8] = pL1;
  if (t < 64) sqt[0][t] = sqn[gbase + t];
  {
    const size_t rb = (size_t)(gbase + 64 + l) * 64;
    pH0 = *(const uint4*)&hH[rb + w * 8];
    pH1 = *(const uint4*)&hH[rb + (w + 4) * 8];
    pL0 = *(const uint4*)&hL[rb + w * 8];
    pL1 = *(const uint4*)&hL[rb + (w + 4) * 8];
  }
  __syncthreads();

  int cur = 0;
  for (int jt = 0; jt < Nn; jt += 64) {
    if (jt + 64 < Nn) {
      short* BH1 = &Bbuf[cur ^ 1][0][0];
      short* BL1 = &Bbuf[cur ^ 1][1][0];
      *(uint4*)&BH1[l * LDB + w * 8]       = pH0;
      *(uint4*)&BH1[l * LDB + (w + 4) * 8] = pH1;
      *(uint4*)&BL1[l * LDB + w * 8]       = pL0;
      *(uint4*)&BL1[l * LDB + (w + 4) * 8] = pL1;
      if (t < 64) sqt[cur ^ 1][t] = sqn[gbase + jt + 64 + t];
      if (jt + 128 < Nn) {
        const size_t rb = (size_t)(gbase + jt + 128 + l) * 64;
        pH0 = *(const uint4*)&hH[rb + w * 8];
        pH1 = *(const uint4*)&hH[rb + (w + 4) * 8];
        pL0 = *(const uint4*)&hL[rb + w * 8];
        pL1 = *(const uint4*)&hL[rb + (w + 4) * 8];
      }
    }

    const short* BH = &Bbuf[cur][0][0];
    const short* BL = &Bbuf[cur][1][0];
    f32x4 d0, d1, d2, d3;
    {
      const int co = (0 * 16 + rl) * LDB;
      s16x8 bh0 = *(const s16x8*)&BH[co + kb * 8];
      s16x8 bh1 = *(const s16x8*)&BH[co + 32 + kb * 8];
      s16x8 bl0 = *(const s16x8*)&BL[co + kb * 8];
      s16x8 bl1 = *(const s16x8*)&BL[co + 32 + kb * 8];
      f32x4 a = (f32x4){0.f, 0.f, 0.f, 0.f};
      a = mfma16(bh0, aH0, a); a = mfma16(bl0, aH0, a);
      a = mfma16(bh0, aL0, a); a = mfma16(bl0, aL0, a);
      a = mfma16(bh1, aH1, a); a = mfma16(bl1, aH1, a);
      a = mfma16(bh1, aL1, a); a = mfma16(bl1, aL1, a);
      d0 = a;
    }
    {
      const int co = (1 * 16 + rl) * LDB;
      s16x8 bh0 = *(const s16x8*)&BH[co + kb * 8];
      s16x8 bh1 = *(const s16x8*)&BH[co + 32 + kb * 8];
      s16x8 bl0 = *(const s16x8*)&BL[co + kb * 8];
      s16x8 bl1 = *(const s16x8*)&BL[co + 32 + kb * 8];
      f32x4 a = (f32x4){0.f, 0.f, 0.f, 0.f};
      a = mfma16(bh0, aH0, a); a = mfma16(bl0, aH0, a);
      a = mfma16(bh0, aL0, a); a = mfma16(bl0, aL0, a);
      a = mfma16(bh1, aH1, a); a = mfma16(bl1, aH1, a);
      a = mfma16(bh1, aL1, a); a = mfma16(bl1, aL1, a);
      d1 = a;
    }
    {
      const int co = (2 * 16 + rl) * LDB;
      s16x8 bh0 = *(const s16x8*)&BH[co + kb * 8];
      s16x8 bh1 = *(const s16x8*)&BH[co + 32 + kb * 8];
      s16x8 bl0 = *(const s16x8*)&BL[co + kb * 8];
      s16x8 bl1 = *(const s16x8*)&BL[co + 32 + kb * 8];
      f32x4 a = (f32x4){0.f, 0.f, 0.f, 0.f};
      a = mfma16(bh0, aH0, a); a = mfma16(bl0, aH0, a);
      a = mfma16(bh0, aL0, a); a = mfma16(bl0, aL0, a);
      a = mfma16(bh1, aH1, a); a = mfma16(bl1, aH1, a);
      a = mfma16(bh1, aL1, a); a = mfma16(bl1, aL1, a);
      d2 = a;
    }
    {
      const int co = (3 * 16 + rl) * LDB;
      s16x8 bh0 = *(const s16x8*)&BH[co + kb * 8];
      s16x8 bh1 = *(const s16x8*)&BH[co + 32 + kb * 8];
      s16x8 bl0 = *(const s16x8*)&BL[co + kb * 8];
      s16x8 bl1 = *(const s16x8*)&BL[co + 32 + kb * 8];
      f32x4 a = (f32x4){0.f, 0.f, 0.f, 0.f};
      a = mfma16(bh0, aH0, a); a = mfma16(bl0, aH0, a);
      a = mfma16(bh0, aL0, a); a = mfma16(bl0, aL0, a);
      a = mfma16(bh1, aH1, a); a = mfma16(bl1, aH1, a);
      a = mfma16(bh1, aL1, a); a = mfma16(bl1, aL1, a);
      d3 = a;
    }
    {
      float4 sj = *(const float4*)&sqt[cur][0 * 16 + kb * 4];
      int jb = jt + 0 * 16 + kb * 4;
      ins(sj.x - 2.f * d0[0], jb + 0); ins(sj.y - 2.f * d0[1], jb + 1);
      ins(sj.z - 2.f * d0[2], jb + 2); ins(sj.w - 2.f * d0[3], jb + 3);
    }
    {
      float4 sj = *(const float4*)&sqt[cur][1 * 16 + kb * 4];
      int jb = jt + 1 * 16 + kb * 4;
      ins(sj.x - 2.f * d1[0], jb + 0); ins(sj.y - 2.f * d1[1], jb + 1);
      ins(sj.z - 2.f * d1[2], jb + 2); ins(sj.w - 2.f * d1[3], jb + 3);
    }
    {
      float4 sj = *(const float4*)&sqt[cur][2 * 16 + kb * 4];
      int jb = jt + 2 * 16 + kb * 4;
      ins(sj.x - 2.f * d2[0], jb + 0); ins(sj.y - 2.f * d2[1], jb + 1);
      ins(sj.z - 2.f * d2[2], jb + 2); ins(sj.w - 2.f * d2[3], jb + 3);
    }
    {
      float4 sj = *(const float4*)&sqt[cur][3 * 16 + kb * 4];
      int jb = jt + 3 * 16 + kb * 4;
      ins(sj.x - 2.f * d3[0], jb + 0); ins(sj.y - 2.f * d3[1], jb + 1);
      ins(sj.z - 2.f * d3[2], jb + 2); ins(sj.w - 2.f * d3[3], jb + 3);
    }
    __syncthreads();   // single barrier per tile
    cur ^= 1;
  }

  // ---- merge 4 sorted-10s per row -> top-10 (B buffers dead; aliased) ----
  {
    const int row = w * 16 + rl;
    float* rd = md + row * LDM + kb * 10;
    int*   ri = mi + row * LDM + kb * 10;
    rd[0] = bd0; rd[1] = bd1; rd[2] = bd2; rd[3] = bd3; rd[4] = bd4;
    rd[5] = bd5; rd[6] = bd6; rd[7] = bd7; rd[8] = bd8; rd[9] = bd9;
    ri[0] = bj0; ri[1] = bj1; ri[2] = bj2; ri[3] = bj3; ri[4] = bj4;
    ri[5] = bj5; ri[6] = bj6; ri[7] = bj7; ri[8] = bj8; ri[9] = bj9;
  }
  __syncthreads();
  if (t < 64) {
    float* rd = md + t * LDM;
    int*   ri = mi + t * LDM;
    #pragma unroll 1
    for (int q = 0; q < Kk; ++q) {
      float best = INFINITY;
      int besti = 0x7fffffff, bslot = 0;
      #pragma unroll 1
      for (int e = 0; e < 40; ++e) {
        float d = rd[e];
        int ix = ri[e];
        bool g = (d < best) || (d == best && ix < besti);
        if (g) { best = d; besti = ix; bslot = e; }
      }
      rd[bslot] = INFINITY;
      idxout[(size_t)(gbase + i0 + t) * Kk + q] = besti;
    }
  }
}

// ---------------- fused agg (+ next-layer uv + sq) ----------------
template <bool FUSE>
__global__ __launch_bounds__(256) void aggF_kernel(const float* __restrict__ U,
                                                   const float* __restrict__ V,
                                                   const int* __restrict__ idx,
                                                   const float* __restrict__ bias,
                                                   short* __restrict__ hH,
                                                   short* __restrict__ hL,
                                                   const float* __restrict__ W,  // [128][64]
                                                   float* __restrict__ Uo,
                                                   float* __restrict__ Vo,
                                                   float* __restrict__ sqno) {
  __shared__ float Ws[FUSE ? 2 * 64 * 64 : 1];
  __shared__ float hs[FUSE ? 64 : 1][68];
  __shared__ float prt[FUSE ? 64 : 1][4];
  const int t = threadIdx.x;
  const int n0 = blockIdx.x * 64;
  const int r = t >> 2, s = t & 3, o0 = s * 16;
  const int n = n0 + r;
  const int gb = n & ~(Nn - 1);

  if constexpr (FUSE) {
    for (int l = t; l < 2 * 64 * 64; l += 256) Ws[l] = W[l];
  }

  float4 u[4], bb[4], acc[4];
  #pragma unroll
  for (int q = 0; q < 4; ++q) {
    u[q] = *(const float4*)&U[(size_t)n * 64 + o0 + q * 4];
    bb[q] = *(const float4*)&bias[o0 + q * 4];
    acc[q] = make_float4(0.f, 0.f, 0.f, 0.f);
  }
  #pragma unroll
  for (int k = 0; k < Kk; ++k) {
    int j = gb + idx[n * Kk + k];
    #pragma unroll
    for (int q = 0; q < 4; ++q) {
      float4 v = *(const float4*)&V[(size_t)j * 64 + o0 + q * 4];
      acc[q].x += lrelu(u[q].x + v.x + bb[q].x);
      acc[q].y += lrelu(u[q].y + v.y + bb[q].y);
      acc[q].z += lrelu(u[q].z + v.z + bb[q].z);
      acc[q].w += lrelu(u[q].w + v.w + bb[q].w);
    }
  }
  #pragma unroll
  for (int q = 0; q < 4; ++q) {
    ushort4 hv, lv;
    hv.x = f2bf(acc[q].x); lv.x = f2bf(acc[q].x - bf2f(hv.x));
    hv.y = f2bf(acc[q].y); lv.y = f2bf(acc[q].y - bf2f(hv.y));
    hv.z = f2bf(acc[q].z); lv.z = f2bf(acc[q].z - bf2f(hv.z));
    hv.w = f2bf(acc[q].w); lv.w = f2bf(acc[q].w - bf2f(hv.w));
    *(ushort4*)&hH[(size_t)n * 64 + o0 + q * 4] = hv;
    *(ushort4*)&hL[(size_t)n * 64 + o0 + q * 4] = lv;
  }
  if constexpr (!FUSE) return;

  #pragma unroll
  for (int q = 0; q < 4; ++q) *(float4*)&hs[r][o0 + q * 4] = acc[q];
  {
    float p = 0.f;
    #pragma unroll
    for (int q = 0; q < 4; ++q) {
      p += acc[q].x * acc[q].x;
      p += acc[q].y * acc[q].y;
      p += acc[q].z * acc[q].z;
      p += acc[q].w * acc[q].w;
    }
    prt[r][s] = p;
  }
  __syncthreads();
  for (int l = t; l < 64 * 64; l += 256) Ws[l] = Ws[l] - Ws[64 * 64 + l];
  if (s == 0) sqno[n] = ((prt[r][0] + prt[r][1]) + prt[r][2]) + prt[r][3];
  __syncthreads();

  const int o = t & 63;
  for (int g4 = 0; g4 < 64; g4 += 4) {
    const int g = g4 + (t >> 6);
    float uu = 0.f, vv = 0.f;
    for (int f = 0; f < 64; ++f) {
      float hv = hs[g][f];
      uu += hv * Ws[f * 64 + o];
      vv += hv * Ws[64 * 64 + f * 64 + o];
    }
    Uo[(size_t)(n0 + g) * 64 + o] = uu;
    Vo[(size_t)(n0 + g) * 64 + o] = vv;
  }
}

// ---------------- MFMA bf16x2 (hi/lo, 3-term) GEMM, 128x128 tile ----------------
// Global loads hoisted above the first barrier (latency overlaps barrier wait).
template <int MODE>
__global__ __launch_bounds__(256) void mfma_gemm(const short* __restrict__ AH,
                                                 const short* __restrict__ AL,
                                                 const short* __restrict__ BH,
                                                 const short* __restrict__ BL,
                                                 const float* __restrict__ bias,
                                                 short* __restrict__ outH,
                                                 short* __restrict__ outL,
                                                 unsigned* __restrict__ pooled,
                                                 int Msl, int zc, int g0) {
  constexpr int Kdim = (MODE == 0) ? 384 : 512;
  __shared__ short AHs[128][40], ALs[128][40], BHs[128][40], BLs[128][40];
  __shared__ float red[8][132];
  const int t = threadIdx.x;
  const int m0 = blockIdx.y * 128, n0 = blockIdx.x * 128;
  const int w = t >> 6, l = t & 63;
  const int q = w >> 1, p = w & 1, rl = l & 15, kb = l >> 4;
  const int srow = t >> 1, sc = (t & 1) * 16;

  f32x4 acc[4][4];
  #pragma unroll
  for (int m = 0; m < 4; ++m)
    #pragma unroll
    for (int n = 0; n < 4; ++n) acc[m][n] = (f32x4){0.f, 0.f, 0.f, 0.f};

  for (int k0 = 0; k0 < Kdim; k0 += 32) {
    size_t aoff, boff;
    if constexpr (MODE == 0)
      aoff = ((size_t)(k0 >> 6) * Msl + zc + m0 + srow) * 64 + (k0 & 63) + sc;
    else
      aoff = (size_t)(m0 + srow) * 512 + k0 + sc;
    boff = (size_t)(n0 + srow) * Kdim + k0 + sc;
    uint4 ga0 = *(const uint4*)(AH + aoff);
    uint4 ga1 = *(const uint4*)(AH + aoff + 8);
    uint4 gl0 = *(const uint4*)(AL + aoff);
    uint4 gl1 = *(const uint4*)(AL + aoff + 8);
    uint4 gb0 = *(const uint4*)(BH + boff);
    uint4 gb1 = *(const uint4*)(BH + boff + 8);
    uint4 gc0 = *(const uint4*)(BL + boff);
    uint4 gc1 = *(const uint4*)(BL + boff + 8);
    __syncthreads();
    *(uint4*)&AHs[srow][sc]     = ga0;
    *(uint4*)&AHs[srow][sc + 8] = ga1;
    *(uint4*)&ALs[srow][sc]     = gl0;
    *(uint4*)&ALs[srow][sc + 8] = gl1;
    *(uint4*)&BHs[srow][sc]     = gb0;
    *(uint4*)&BHs[srow][sc + 8] = gb1;
    *(uint4*)&BLs[srow][sc]     = gc0;
    *(uint4*)&BLs[srow][sc + 8] = gc1;
    __syncthreads();

    s16x8 aH[4], aL[4], bH[4], bL[4];
    #pragma unroll
    for (int m = 0; m < 4; ++m) {
      aH[m] = *(const s16x8*)&AHs[q * 64 + m * 16 + rl][kb * 8];
      aL[m] = *(const s16x8*)&ALs[q * 64 + m * 16 + rl][kb * 8];
    }
    #pragma unroll
    for (int n = 0; n < 4; ++n) {
      bH[n] = *(const s16x8*)&BHs[p * 64 + n * 16 + rl][kb * 8];
      bL[n] = *(const s16x8*)&BLs[p * 64 + n * 16 + rl][kb * 8];
    }
    #pragma unroll
    for (int m = 0; m < 4; ++m)
      #pragma unroll
      for (int n = 0; n < 4; ++n) {
        acc[m][n] = mfma16(aH[m], bH[n], acc[m][n]);
        acc[m][n] = mfma16(aH[m], bL[n], acc[m][n]);
        acc[m][n] = mfma16(aL[m], bH[n], acc[m][n]);
      }
  }

  if constexpr (MODE == 0) {
    #pragma unroll
    for (int n = 0; n < 4; ++n) {
      const int col = n0 + p * 64 + n * 16 + rl;
      const float bv = bias[col];
      #pragma unroll
      for (int m = 0; m < 4; ++m) {
        #pragma unroll
        for (int rr = 0; rr < 4; ++rr) {
          int row = m0 + q * 64 + m * 16 + kb * 4 + rr;
          float v = lrelu(acc[m][n][rr] + bv);
          unsigned short hv = f2bf(v);
          unsigned short lv = f2bf(v - bf2f(hv));
          outH[(size_t)row * 512 + col] = (short)hv;
          outL[(size_t)row * 512 + col] = (short)lv;
        }
      }
    }
  } else {
    #pragma unroll
    for (int n = 0; n < 4; ++n) {
      float cm = acc[0][n][0];
      #pragma unroll
      for (int m = 0; m < 4; ++m)
        #pragma unroll
        for (int rr = 0; rr < 4; ++rr) cm = fmaxf(cm, acc[m][n][rr]);
      red[q * 4 + kb][p * 64 + n * 16 + rl] = cm;
    }
    __syncthreads();
    if (t < 128) {
      float m = red[0][t];
      #pragma unroll
      for (int rr = 1; rr < 8; ++rr) m = fmaxf(m, red[rr][t]);
      m += bias[n0 + t];
      int g = g0 + ((zc + m0) >> 10);
      atomicMax(&pooled[(size_t)g * 512 + n0 + t], encf(m));
    }
  }
}

// ---------------- head ----------------
__global__ __launch_bounds__(256) void head_kernel(const unsigned* __restrict__ pooled,
                                                   const float* __restrict__ Wm1,
                                                   const float* __restrict__ bm1,
                                                   const float* __restrict__ Wm2,
                                                   const float* __restrict__ bm2,
                                                   float* __restrict__ out) {
  __shared__ float ps[512];
  __shared__ float hs[256];
  int b = blockIdx.x;
  int t = threadIdx.x;
  for (int l = t; l < 512; l += 256) ps[l] = decf(pooled[(size_t)b * 512 + l]);
  __syncthreads();
  float acc = bm1[t];
  for (int f = 0; f < 512; ++f) acc += ps[f] * Wm1[f * 256 + t];
  hs[t] = lrelu(acc);
  __syncthreads();
  if (t < 3) {
    float y = bm2[t];
    for (int f = 0; f < 256; ++f) y += hs[f] * Wm2[f * 3 + t];
    out[b * 3 + t] = y;
  }
}

static inline size_t al256(size_t v) { return (v + 255) & ~(size_t)255; }

extern "C" void kernel_launch(void* const* d_in, const int* in_sizes, int n_in,
                              void* d_out, int out_size, void* d_ws, size_t ws_size,
                              hipStream_t stream) {
  (void)in_sizes; (void)n_in; (void)out_size;
  const float* x    = (const float*)d_in[0];
  const float* pos  = (const float*)d_in[1];
  const float* tq   = (const float*)d_in[2];
  // d_in[3] = batch (uniform & sorted; unused)
  const float* W1   = (const float*)d_in[4];
  const float* b1   = (const float*)d_in[5];
  const float* W2   = (const float*)d_in[6];
  const float* b2   = (const float*)d_in[7];
  const float* Wl1a = (const float*)d_in[8];
  const float* bl1a = (const float*)d_in[9];
  const float* Wl1b = (const float*)d_in[10];
  const float* bl1b = (const float*)d_in[11];
  const float* Wm1  = (const float*)d_in[12];
  const float* bm1  = (const float*)d_in[13];
  const float* Wm2  = (const float*)d_in[14];
  const float* bm2  = (const float*)d_in[15];
  float* out = (float*)d_out;

  // ---- pick largest graph-chunk G whose workspace fits ----
  auto calc = [&](int G, size_t& hHB, size_t& uvB, size_t& uvzB) -> size_t {
    size_t M = (size_t)G * Nn;
    hHB = al256(M * 384 * 2);                 // hH (and hL): 6 slots [M][64] bf16
    uvB = al256(M * 64 * 4);                  // each of Ua,Va,Ub,Vb
    size_t Mz = M < 16384 ? M : 16384;
    size_t zB = 2 * al256(Mz * 512 * 2);      // zH+zL (alias U/V region)
    uvzB = (4 * uvB > zB) ? 4 * uvB : zB;
    size_t convS = al256(M * 5 * 4) + al256(M * 4) + al256(M * Kk * 4);
    size_t wB = 2 * al256((size_t)512 * 384 * 2) + 2 * al256((size_t)512 * 512 * 2);
    return 2 * hHB + uvzB + convS + al256((size_t)Bg * 512 * 4) + wB + 1024;
  };
  int G = 64;
  size_t hHB = 0, uvB = 0, uvzB = 0;
  while (G > 1 && calc(G, hHB, uvB, uvzB) > ws_size) G >>= 1;
  calc(G, hHB, uvB, uvzB);
  const int M = G * Nn;
  const int Mz = M < 16384 ? M : 16384;

  char* w = (char*)d_ws;
  short* hH = (short*)w;
  short* hL = (short*)(w + hHB);
  char*  uvz = w + 2 * hHB;
  float* Ua = (float*)uvz;
  float* Va = (float*)(uvz + uvB);
  float* Ub = (float*)(uvz + 2 * uvB);
  float* Vb = (float*)(uvz + 3 * uvB);
  short* zH = (short*)uvz;                                  // MLP aliases U/V region
  short* zL = (short*)(uvz + al256((size_t)Mz * 512 * 2));
  char*  conv = uvz + uvzB;
  float* xx  = (float*)conv;
  float* sqn = (float*)(conv + al256((size_t)M * 5 * 4));
  int*   idx = (int*)((char*)sqn + al256((size_t)M * 4));
  unsigned* pooled = (unsigned*)((char*)idx + al256((size_t)M * Kk * 4));
  short* WHa = (short*)((char*)pooled + al256((size_t)Bg * 512 * 4));
  short* WLa = WHa + (size_t)512 * 384;
  short* WHb = (short*)((char*)WHa + 2 * al256((size_t)512 * 384 * 2));
  short* WLb = WHb + (size_t)512 * 512;

  wprep<384><<<(384 * 512) / 256, 256, 0, stream>>>(Wl1a, WHa, WLa);
  wprep<512><<<(512 * 512) / 256, 256, 0, stream>>>(Wl1b, WHb, WLb);
  pooled_init<<<(Bg * 512) / 256, 256, 0, stream>>>(pooled);

  for (int g0 = 0; g0 < Bg; g0 += G) {
    build_xx<<<M / 256, 256, 0, stream>>>(x, pos, tq, xx, sqn, g0 * Nn);

    // conv1 (F=5, W1) -> slot 0; fused uv(conv2)+sq
    uv_kernel<5><<<M / 16, 256, 0, stream>>>(xx, W1, Ua, Va);
    knn_kernel<5><<<dim3(Nn / 64, G), 256, 0, stream>>>(xx, sqn, idx);

    float *Ui = Ua, *Vi = Va, *Uo = Ub, *Vo = Vb;
    aggF_kernel<true><<<M / 64, 256, 0, stream>>>(Ui, Vi, idx, b1, hH, hL,
                                                  W2, Uo, Vo, sqn);
    { float* tp = Ui; Ui = Uo; Uo = tp; tp = Vi; Vi = Vo; Vo = tp; }

    // conv2..6 -> slots 1..5
    for (int c = 1; c < 6; ++c) {
      knn64_mfma<<<dim3(Nn / 64, G), 256, 0, stream>>>(hH + (size_t)(c - 1) * M * 64,
                                                       hL + (size_t)(c - 1) * M * 64,
                                                       sqn, idx);
      if (c < 5) {
        aggF_kernel<true><<<M / 64, 256, 0, stream>>>(Ui, Vi, idx, b2,
                                                      hH + (size_t)c * M * 64,
                                                      hL + (size_t)c * M * 64,
                                                      W2, Uo, Vo, sqn);
        { float* tp = Ui; Ui = Uo; Uo = tp; tp = Vi; Vi = Vo; Vo = tp; }
      } else {
        aggF_kernel<false><<<M / 64, 256, 0, stream>>>(Ui, Vi, idx, b2,
                                                       hH + (size_t)5 * M * 64,
                                                       hL + (size_t)5 * M * 64,
                                                       nullptr, nullptr, nullptr, nullptr);
      }
    }

    // MLP over this chunk's rows, z-chunked
    for (int zc = 0; zc < M; zc += Mz) {
      mfma_gemm<0><<<dim3(4, Mz / 128), 256, 0, stream>>>(hH, hL, WHa, WLa, bl1a,
                                                          zH, zL, nullptr, M, zc, 0);
      mfma_gemm<1><<<dim3(4, Mz / 128), 256, 0, stream>>>(zH, zL, WHb, WLb, bl1b,
                                                          nullptr, nullptr, pooled, Mz, zc, g0);
    }
  }

  head_kernel<<<Bg, 256, 0, stream>>>(pooled, Wm1, bm1, Wm2, bm2, out);
}

// Round 17
// 1528.010 us; speedup vs baseline: 1.3141x; 1.0061x over previous
//
#include <hip/hip_runtime.h>
#include <cstdint>
#include <cstddef>

constexpr int Bg = 64;     // graphs
constexpr int Nn = 1024;   // nodes per graph
constexpr int Kk = 10;     // kNN neighbors
constexpr int BN = Bg * Nn;
#define SLOPE 0.01f

typedef __attribute__((ext_vector_type(8))) short s16x8;
typedef __attribute__((ext_vector_type(4))) float f32x4;

__device__ __forceinline__ float lrelu(float v) { return v >= 0.f ? v : SLOPE * v; }

__device__ __forceinline__ unsigned encf(float f) {
  unsigned u = __float_as_uint(f);
  return (u & 0x80000000u) ? ~u : (u | 0x80000000u);
}
__device__ __forceinline__ float decf(unsigned e) {
  unsigned u = (e & 0x80000000u) ? (e & 0x7fffffffu) : ~e;
  return __uint_as_float(u);
}
__device__ __forceinline__ unsigned short f2bf(float f) {
  unsigned u = __float_as_uint(f);
  return (unsigned short)((u + 0x7FFFu + ((u >> 16) & 1u)) >> 16);
}
__device__ __forceinline__ float bf2f(unsigned short h) {
  return __uint_as_float(((unsigned)h) << 16);
}

__device__ __forceinline__ f32x4 mfma16(s16x8 a, s16x8 b, f32x4 c) {
  return __builtin_amdgcn_mfma_f32_16x16x32_bf16(a, b, c, 0, 0, 0);
}

__global__ __launch_bounds__(256) void pooled_init(unsigned* __restrict__ p) {
  p[blockIdx.x * 256 + threadIdx.x] = 0u;
}

// ---------------- build xx = [tq, x, pos] + fused sq (exact shfl-tree order) ----------------
__global__ __launch_bounds__(256) void build_xx(const float* __restrict__ x,
                                                const float* __restrict__ pos,
                                                const float* __restrict__ tq,
                                                float* __restrict__ xx,
                                                float* __restrict__ sqn, int rowoff) {
  int n = blockIdx.x * 256 + threadIdx.x;
  int g = rowoff + n;
  float v0 = tq[g], v1 = x[g];
  float v2 = pos[g * 3 + 0], v3 = pos[g * 3 + 1], v4 = pos[g * 3 + 2];
  xx[n * 5 + 0] = v0;
  xx[n * 5 + 1] = v1;
  xx[n * 5 + 2] = v2;
  xx[n * 5 + 3] = v3;
  xx[n * 5 + 4] = v4;
  float s0 = v0 * v0, s1 = v1 * v1, s2 = v2 * v2, s3 = v3 * v3, s4 = v4 * v4;
  sqn[n] = ((s0 + s4) + s2) + (s1 + s3);   // == sq_kernel's 64-lane shfl tree for F=5
}

// ---------------- weight prep: W[K][512] f32 -> WH/WL [512][K] bf16 ----------------
template <int K>
__global__ __launch_bounds__(256) void wprep(const float* __restrict__ W,
                                             short* __restrict__ WH,
                                             short* __restrict__ WL) {
  int idx = blockIdx.x * 256 + threadIdx.x;
  int k = idx >> 9, n = idx & 511;
  float v = W[idx];
  unsigned short h = f2bf(v);
  unsigned short lo = f2bf(v - bf2f(h));
  WH[(size_t)n * K + k] = (short)h;
  WL[(size_t)n * K + k] = (short)lo;
}

// ---------------- U = h @ (Wt - Wb), V = h @ Wb  (conv1 only, F=5) ----------------
template <int F>
__global__ __launch_bounds__(256) void uv_kernel(const float* __restrict__ h,
                                                 const float* __restrict__ W,  // [2F][64]
                                                 float* __restrict__ U,
                                                 float* __restrict__ V) {
  __shared__ float Ws[2 * F * 64];
  __shared__ float hs[16 * F];
  const int t = threadIdx.x;
  const int n0 = blockIdx.x * 16;
  for (int l = t; l < 2 * F * 64; l += 256) Ws[l] = W[l];
  for (int l = t; l < 16 * F; l += 256) hs[l] = h[(size_t)n0 * F + l];
  __syncthreads();
  for (int l = t; l < F * 64; l += 256) Ws[l] = Ws[l] - Ws[F * 64 + l];
  __syncthreads();
  const int o = t & 63;
  #pragma unroll
  for (int g4 = 0; g4 < 16; g4 += 4) {
    const int g = g4 + (t >> 6);
    float u = 0.f, v = 0.f;
    for (int f = 0; f < F; ++f) {
      float hv = hs[g * F + f];
      u += hv * Ws[f * 64 + o];
      v += hv * Ws[F * 64 + f * 64 + o];
    }
    U[(size_t)(n0 + g) * 64 + o] = u;
    V[(size_t)(n0 + g) * 64 + o] = v;
  }
}

// Branchless sorted top-10 (d,j) ladder, monotone-compare form (round-13 proven).
#define LADDER_STATE                                                                     \
  float bd0 = INFINITY, bd1 = INFINITY, bd2 = INFINITY, bd3 = INFINITY, bd4 = INFINITY,  \
        bd5 = INFINITY, bd6 = INFINITY, bd7 = INFINITY, bd8 = INFINITY, bd9 = INFINITY;  \
  int bj0 = 0x7fffffff, bj1 = 0x7fffffff, bj2 = 0x7fffffff, bj3 = 0x7fffffff,            \
      bj4 = 0x7fffffff, bj5 = 0x7fffffff, bj6 = 0x7fffffff, bj7 = 0x7fffffff,            \
      bj8 = 0x7fffffff, bj9 = 0x7fffffff;

#define LADDER_INS                                                                        \
  auto ins = [&](float kd, int kj) {                                                      \
    bool m0 = kd < bd0; bool m1 = kd < bd1; bool m2 = kd < bd2; bool m3 = kd < bd3;       \
    bool m4 = kd < bd4; bool m5 = kd < bd5; bool m6 = kd < bd6; bool m7 = kd < bd7;       \
    bool m8 = kd < bd8; bool m9 = kd < bd9;                                               \
    bd9 = m8 ? bd8 : (m9 ? kd : bd9); bj9 = m8 ? bj8 : (m9 ? kj : bj9);                   \
    bd8 = m7 ? bd7 : (m8 ? kd : bd8); bj8 = m7 ? bj7 : (m8 ? kj : bj8);                   \
    bd7 = m6 ? bd6 : (m7 ? kd : bd7); bj7 = m6 ? bj6 : (m7 ? kj : bj7);                   \
    bd6 = m5 ? bd5 : (m6 ? kd : bd6); bj6 = m5 ? bj5 : (m6 ? kj : bj6);                   \
    bd5 = m4 ? bd4 : (m5 ? kd : bd5); bj5 = m4 ? bj4 : (m5 ? kj : bj5);                   \
    bd4 = m3 ? bd3 : (m4 ? kd : bd4); bj4 = m3 ? bj3 : (m4 ? kj : bj4);                   \
    bd3 = m2 ? bd2 : (m3 ? kd : bd3); bj3 = m2 ? bj2 : (m3 ? kj : bj3);                   \
    bd2 = m1 ? bd1 : (m2 ? kd : bd2); bj2 = m1 ? bj1 : (m2 ? kj : bj2);                   \
    bd1 = m0 ? bd0 : (m1 ? kd : bd1); bj1 = m0 ? bj0 : (m1 ? kj : bj1);                   \
    bd0 = m0 ? kd : bd0;              bj0 = m0 ? kj : bj0;                                \
  };

#define FMA16(av, bv)                                                        \
  do {                                                                       \
    acc[0][0] += av.x * bv.x; acc[0][1] += av.x * bv.y;                      \
    acc[0][2] += av.x * bv.z; acc[0][3] += av.x * bv.w;                      \
    acc[1][0] += av.y * bv.x; acc[1][1] += av.y * bv.y;                      \
    acc[1][2] += av.y * bv.z; acc[1][3] += av.y * bv.w;                      \
    acc[2][0] += av.z * bv.x; acc[2][1] += av.z * bv.y;                      \
    acc[2][2] += av.z * bv.z; acc[2][3] += av.z * bv.w;                      \
    acc[3][0] += av.w * bv.x; acc[3][1] += av.w * bv.y;                      \
    acc[3][2] += av.w * bv.z; acc[3][3] += av.w * bv.w;                      \
  } while (0)

// ---------------- kNN (F=5, fp32 VALU path; round-13 proven) ----------------
template <int F>
__global__ __launch_bounds__(256) void knn_kernel(const float* __restrict__ h,
                                                  const float* __restrict__ sqn,
                                                  int* __restrict__ idxout) {
  constexpr int IPB = 64;
  constexpr int TJ = 64;
  constexpr int LDA = 68;
  constexpr int LDD = 65;
  constexpr int LDM = 41;
  constexpr int UNI = (IPB * LDM * 2 > TJ * LDA) ? IPB * LDM * 2 : TJ * LDA;
  __shared__ float As[F][LDA];
  __shared__ float uni[UNI];
  __shared__ float sqt[TJ];
  float* Bs = uni;
  float* D  = uni;
  float* md = uni;
  int*   mi = (int*)(uni + IPB * LDM);

  const int b = blockIdx.y;
  const int i0 = blockIdx.x * IPB;
  const int t = threadIdx.x;
  const int tx = t & 15, ty = t >> 4;
  const int gbase = b * Nn;
  const int r = t & 63;
  const int s = t >> 6;

  for (int l = t; l < IPB * F; l += 256) {
    int row = l / F, f = l % F;
    As[f][row] = h[(size_t)(gbase + i0 + row) * F + f];
  }

  LADDER_STATE
  LADDER_INS

  for (int jt = 0; jt < Nn; jt += TJ) {
    __syncthreads();
    for (int l = t; l < TJ * F; l += 256) {
      int row = l / F, f = l % F;
      Bs[f * LDA + row] = h[(size_t)(gbase + jt + row) * F + f];
    }
    if (t < TJ) sqt[t] = sqn[gbase + jt + t];
    __syncthreads();

    float acc[4][4] = {{0.f, 0.f, 0.f, 0.f}, {0.f, 0.f, 0.f, 0.f},
                       {0.f, 0.f, 0.f, 0.f}, {0.f, 0.f, 0.f, 0.f}};
    #pragma unroll
    for (int f = 0; f < F; ++f) {
      float4 av = *(const float4*)&As[f][ty * 4];
      float4 bv = *(const float4*)(Bs + f * LDA + tx * 4);
      FMA16(av, bv);
    }
    __syncthreads();

    float4 sj = *(const float4*)&sqt[tx * 4];
    #pragma unroll
    for (int ii = 0; ii < 4; ++ii) {
      float* dr = D + (ty * 4 + ii) * LDD + tx * 4;
      dr[0] = sj.x - 2.f * acc[ii][0];
      dr[1] = sj.y - 2.f * acc[ii][1];
      dr[2] = sj.z - 2.f * acc[ii][2];
      dr[3] = sj.w - 2.f * acc[ii][3];
    }
    __syncthreads();

    {
      const float* drow = D + r * LDD + s * 16;
      float dv[16];
      #pragma unroll
      for (int qq = 0; qq < 16; ++qq) dv[qq] = drow[qq];
      #pragma unroll
      for (int qq = 0; qq < 16; ++qq) ins(dv[qq], jt + s * 16 + qq);
    }
  }

  __syncthreads();
  {
    float* rd = md + r * LDM + s * 10;
    int*   ri = mi + r * LDM + s * 10;
    rd[0] = bd0; rd[1] = bd1; rd[2] = bd2; rd[3] = bd3; rd[4] = bd4;
    rd[5] = bd5; rd[6] = bd6; rd[7] = bd7; rd[8] = bd8; rd[9] = bd9;
    ri[0] = bj0; ri[1] = bj1; ri[2] = bj2; ri[3] = bj3; ri[4] = bj4;
    ri[5] = bj5; ri[6] = bj6; ri[7] = bj7; ri[8] = bj8; ri[9] = bj9;
  }
  __syncthreads();
  if (s == 0) {
    float* rd = md + r * LDM;
    int*   ri = mi + r * LDM;
    #pragma unroll 1
    for (int q = 0; q < Kk; ++q) {
      float best = INFINITY;
      int besti = 0x7fffffff, bslot = 0;
      #pragma unroll 1
      for (int e = 0; e < 40; ++e) {
        float d = rd[e];
        int ix = ri[e];
        bool g = (d < best) || (d == best && ix < besti);
        if (g) { best = d; besti = ix; bslot = e; }
      }
      rd[bslot] = INFINITY;
      idxout[(size_t)(gbase + i0 + r) * Kk + q] = besti;
    }
  }
}

// ---------------- kNN (F=64) v3: swapped-operand MFMA, in-register distances ----------------
// (round-14 proven: 153 us, VGPR 52, bit-identical distances via commutated mfma)
__global__ __launch_bounds__(256) void knn64_mfma(const short* __restrict__ hH,
                                                  const short* __restrict__ hL,
                                                  const float* __restrict__ sqn,
                                                  int* __restrict__ idxout) {
  constexpr int LDB = 72;   // shorts per row (144B, 16B-aligned)
  constexpr int LDM = 41;
  __shared__ __align__(16) short Bbuf[2][2][64 * LDB];  // [buf][H/L] = 36864 B
  __shared__ float sqt[2][64];
  float* md = (float*)&Bbuf[0][0][0];          // merge aliases dead B buffers at end
  int*   mi = (int*)(md + 64 * LDM);

  const int b = blockIdx.y;
  const int i0 = blockIdx.x * 64;
  const int t = threadIdx.x;
  const int w = t >> 6, l = t & 63;
  const int rl = l & 15, kb = l >> 4;
  const int gbase = b * Nn;

  s16x8 aH0, aH1, aL0, aL1;
  {
    const size_t ar = (size_t)(gbase + i0 + w * 16 + rl) * 64;
    aH0 = *(const s16x8*)&hH[ar + kb * 8];
    aH1 = *(const s16x8*)&hH[ar + 32 + kb * 8];
    aL0 = *(const s16x8*)&hL[ar + kb * 8];
    aL1 = *(const s16x8*)&hL[ar + 32 + kb * 8];
  }

  LADDER_STATE
  LADDER_INS

  uint4 pH0, pH1, pL0, pL1;
  {
    const size_t rb = (size_t)(gbase + l) * 64;
    pH0 = *(const uint4*)&hH[rb + w * 8];
    pH1 = *(const uint4*)&hH[rb + (w + 4) * 8];
    pL0 = *(const uint4*)&hL[rb + w * 8];
    pL1 = *(const uint4*)&hL[rb + (w + 4) * 8];
  }
  *(uint4*)&Bbuf[0][0][l * LDB + w * 8]       = pH0;
  *(uint4*)&Bbuf[0][0][l * LDB + (w + 4) * 8] = pH1;
  *(uint4*)&Bbuf[0][1][l * LDB + w * 8]       = pL0;
  *(uint4*)&Bbuf[0][1][l * LDB + (w + 4) * 8] = pL1;
  if (t < 64) sqt[0][t] = sqn[gbase + t];
  {
    const size_t rb = (size_t)(gbase + 64 + l) * 64;
    pH0 = *(const uint4*)&hH[rb + w * 8];
    pH1 = *(const uint4*)&hH[rb + (w + 4) * 8];
    pL0 = *(const uint4*)&hL[rb + w * 8];
    pL1 = *(const uint4*)&hL[rb + (w + 4) * 8];
  }
  __syncthreads();

  int cur = 0;
  for (int jt = 0; jt < Nn; jt += 64) {
    if (jt + 64 < Nn) {
      short* BH1 = &Bbuf[cur ^ 1][0][0];
      short* BL1 = &Bbuf[cur ^ 1][1][0];
      *(uint4*)&BH1[l * LDB + w * 8]       = pH0;
      *(uint4*)&BH1[l * LDB + (w + 4) * 8] = pH1;
      *(uint4*)&BL1[l * LDB + w * 8]       = pL0;
      *(uint4*)&BL1[l * LDB + (w + 4) * 8] = pL1;
      if (t < 64) sqt[cur ^ 1][t] = sqn[gbase + jt + 64 + t];
      if (jt + 128 < Nn) {
        const size_t rb = (size_t)(gbase + jt + 128 + l) * 64;
        pH0 = *(const uint4*)&hH[rb + w * 8];
        pH1 = *(const uint4*)&hH[rb + (w + 4) * 8];
        pL0 = *(const uint4*)&hL[rb + w * 8];
        pL1 = *(const uint4*)&hL[rb + (w + 4) * 8];
      }
    }

    const short* BH = &Bbuf[cur][0][0];
    const short* BL = &Bbuf[cur][1][0];
    f32x4 d0, d1, d2, d3;
    {
      const int co = (0 * 16 + rl) * LDB;
      s16x8 bh0 = *(const s16x8*)&BH[co + kb * 8];
      s16x8 bh1 = *(const s16x8*)&BH[co + 32 + kb * 8];
      s16x8 bl0 = *(const s16x8*)&BL[co + kb * 8];
      s16x8 bl1 = *(const s16x8*)&BL[co + 32 + kb * 8];
      f32x4 a = (f32x4){0.f, 0.f, 0.f, 0.f};
      a = mfma16(bh0, aH0, a); a = mfma16(bl0, aH0, a);
      a = mfma16(bh0, aL0, a); a = mfma16(bl0, aL0, a);
      a = mfma16(bh1, aH1, a); a = mfma16(bl1, aH1, a);
      a = mfma16(bh1, aL1, a); a = mfma16(bl1, aL1, a);
      d0 = a;
    }
    {
      const int co = (1 * 16 + rl) * LDB;
      s16x8 bh0 = *(const s16x8*)&BH[co + kb * 8];
      s16x8 bh1 = *(const s16x8*)&BH[co + 32 + kb * 8];
      s16x8 bl0 = *(const s16x8*)&BL[co + kb * 8];
      s16x8 bl1 = *(const s16x8*)&BL[co + 32 + kb * 8];
      f32x4 a = (f32x4){0.f, 0.f, 0.f, 0.f};
      a = mfma16(bh0, aH0, a); a = mfma16(bl0, aH0, a);
      a = mfma16(bh0, aL0, a); a = mfma16(bl0, aL0, a);
      a = mfma16(bh1, aH1, a); a = mfma16(bl1, aH1, a);
      a = mfma16(bh1, aL1, a); a = mfma16(bl1, aL1, a);
      d1 = a;
    }
    {
      const int co = (2 * 16 + rl) * LDB;
      s16x8 bh0 = *(const s16x8*)&BH[co + kb * 8];
      s16x8 bh1 = *(const s16x8*)&BH[co + 32 + kb * 8];
      s16x8 bl0 = *(const s16x8*)&BL[co + kb * 8];
      s16x8 bl1 = *(const s16x8*)&BL[co + 32 + kb * 8];
      f32x4 a = (f32x4){0.f, 0.f, 0.f, 0.f};
      a = mfma16(bh0, aH0, a); a = mfma16(bl0, aH0, a);
      a = mfma16(bh0, aL0, a); a = mfma16(bl0, aL0, a);
      a = mfma16(bh1, aH1, a); a = mfma16(bl1, aH1, a);
      a = mfma16(bh1, aL1, a); a = mfma16(bl1, aL1, a);
      d2 = a;
    }
    {
      const int co = (3 * 16 + rl) * LDB;
      s16x8 bh0 = *(const s16x8*)&BH[co + kb * 8];
      s16x8 bh1 = *(const s16x8*)&BH[co + 32 + kb * 8];
      s16x8 bl0 = *(const s16x8*)&BL[co + kb * 8];
      s16x8 bl1 = *(const s16x8*)&BL[co + 32 + kb * 8];
      f32x4 a = (f32x4){0.f, 0.f, 0.f, 0.f};
      a = mfma16(bh0, aH0, a); a = mfma16(bl0, aH0, a);
      a = mfma16(bh0, aL0, a); a = mfma16(bl0, aL0, a);
      a = mfma16(bh1, aH1, a); a = mfma16(bl1, aH1, a);
      a = mfma16(bh1, aL1, a); a = mfma16(bl1, aL1, a);
      d3 = a;
    }
    {
      float4 sj = *(const float4*)&sqt[cur][0 * 16 + kb * 4];
      int jb = jt + 0 * 16 + kb * 4;
      ins(sj.x - 2.f * d0[0], jb + 0); ins(sj.y - 2.f * d0[1], jb + 1);
      ins(sj.z - 2.f * d0[2], jb + 2); ins(sj.w - 2.f * d0[3], jb + 3);
    }
    {
      float4 sj = *(const float4*)&sqt[cur][1 * 16 + kb * 4];
      int jb = jt + 1 * 16 + kb * 4;
      ins(sj.x - 2.f * d1[0], jb + 0); ins(sj.y - 2.f * d1[1], jb + 1);
      ins(sj.z - 2.f * d1[2], jb + 2); ins(sj.w - 2.f * d1[3], jb + 3);
    }
    {
      float4 sj = *(const float4*)&sqt[cur][2 * 16 + kb * 4];
      int jb = jt + 2 * 16 + kb * 4;
      ins(sj.x - 2.f * d2[0], jb + 0); ins(sj.y - 2.f * d2[1], jb + 1);
      ins(sj.z - 2.f * d2[2], jb + 2); ins(sj.w - 2.f * d2[3], jb + 3);
    }
    {
      float4 sj = *(const float4*)&sqt[cur][3 * 16 + kb * 4];
      int jb = jt + 3 * 16 + kb * 4;
      ins(sj.x - 2.f * d3[0], jb + 0); ins(sj.y - 2.f * d3[1], jb + 1);
      ins(sj.z - 2.f * d3[2], jb + 2); ins(sj.w - 2.f * d3[3], jb + 3);
    }
    __syncthreads();   // single barrier per tile
    cur ^= 1;
  }

  {
    const int row = w * 16 + rl;
    float* rd = md + row * LDM + kb * 10;
    int*   ri = mi + row * LDM + kb * 10;
    rd[0] = bd0; rd[1] = bd1; rd[2] = bd2; rd[3] = bd3; rd[4] = bd4;
    rd[5] = bd5; rd[6] = bd6; rd[7] = bd7; rd[8] = bd8; rd[9] = bd9;
    ri[0] = bj0; ri[1] = bj1; ri[2] = bj2; ri[3] = bj3; ri[4] = bj4;
    ri[5] = bj5; ri[6] = bj6; ri[7] = bj7; ri[8] = bj8; ri[9] = bj9;
  }
  __syncthreads();
  if (t < 64) {
    float* rd = md + t * LDM;
    int*   ri = mi + t * LDM;
    #pragma unroll 1
    for (int q = 0; q < Kk; ++q) {
      float best = INFINITY;
      int besti = 0x7fffffff, bslot = 0;
      #pragma unroll 1
      for (int e = 0; e < 40; ++e) {
        float d = rd[e];
        int ix = ri[e];
        bool g = (d < best) || (d == best && ix < besti);
        if (g) { best = d; besti = ix; bslot = e; }
      }
      rd[bslot] = INFINITY;
      idxout[(size_t)(gbase + i0 + t) * Kk + q] = besti;
    }
  }
}

// ---------------- fused agg (+ next-layer uv + sq), transposed-Ws b128 reads ----------------
template <bool FUSE>
__global__ __launch_bounds__(256) void aggF_kernel(const float* __restrict__ U,
                                                   const float* __restrict__ V,
                                                   const int* __restrict__ idx,
                                                   const float* __restrict__ bias,
                                                   short* __restrict__ hH,
                                                   short* __restrict__ hL,
                                                   const float* __restrict__ W,  // [128][64]
                                                   float* __restrict__ Uo,
                                                   float* __restrict__ Vo,
                                                   float* __restrict__ sqno) {
  constexpr int LWT = 68;  // pitch (floats): rows 16B-aligned, optimal 8-pass b128 banking
  __shared__ float WsT [FUSE ? 64 * LWT : 1];   // (Wt-Wb)^T : WsT [o*LWT + f]
  __shared__ float WsT2[FUSE ? 64 * LWT : 1];   // Wb^T      : WsT2[o*LWT + f]
  __shared__ float hs[FUSE ? 64 : 1][68];
  __shared__ float prt[FUSE ? 64 : 1][4];
  const int t = threadIdx.x;
  const int n0 = blockIdx.x * 64;
  const int r = t >> 2, s = t & 3, o0 = s * 16;
  const int n = n0 + r;
  const int gb = n & ~(Nn - 1);

  if constexpr (FUSE) {
    // transposed load; subtract folded in (same f32 values as old Ws path)
    for (int l = t; l < 64 * 64; l += 256) {
      int f = l >> 6, o = l & 63;
      float wt = W[l];             // W[f][o]
      float wb = W[64 * 64 + l];   // W[64+f][o]
      WsT [o * LWT + f] = wt - wb;
      WsT2[o * LWT + f] = wb;
    }
  }

  float4 u[4], bb[4], acc[4];
  #pragma unroll
  for (int q = 0; q < 4; ++q) {
    u[q] = *(const float4*)&U[(size_t)n * 64 + o0 + q * 4];
    bb[q] = *(const float4*)&bias[o0 + q * 4];
    acc[q] = make_float4(0.f, 0.f, 0.f, 0.f);
  }
  #pragma unroll
  for (int k = 0; k < Kk; ++k) {
    int j = gb + idx[n * Kk + k];
    #pragma unroll
    for (int q = 0; q < 4; ++q) {
      float4 v = *(const float4*)&V[(size_t)j * 64 + o0 + q * 4];
      acc[q].x += lrelu(u[q].x + v.x + bb[q].x);
      acc[q].y += lrelu(u[q].y + v.y + bb[q].y);
      acc[q].z += lrelu(u[q].z + v.z + bb[q].z);
      acc[q].w += lrelu(u[q].w + v.w + bb[q].w);
    }
  }
  #pragma unroll
  for (int q = 0; q < 4; ++q) {
    ushort4 hv, lv;
    hv.x = f2bf(acc[q].x); lv.x = f2bf(acc[q].x - bf2f(hv.x));
    hv.y = f2bf(acc[q].y); lv.y = f2bf(acc[q].y - bf2f(hv.y));
    hv.z = f2bf(acc[q].z); lv.z = f2bf(acc[q].z - bf2f(hv.z));
    hv.w = f2bf(acc[q].w); lv.w = f2bf(acc[q].w - bf2f(hv.w));
    *(ushort4*)&hH[(size_t)n * 64 + o0 + q * 4] = hv;
    *(ushort4*)&hL[(size_t)n * 64 + o0 + q * 4] = lv;
  }
  if constexpr (!FUSE) return;

  #pragma unroll
  for (int q = 0; q < 4; ++q) *(float4*)&hs[r][o0 + q * 4] = acc[q];
  {
    float p = 0.f;
    #pragma unroll
    for (int q = 0; q < 4; ++q) {
      p += acc[q].x * acc[q].x;
      p += acc[q].y * acc[q].y;
      p += acc[q].z * acc[q].z;
      p += acc[q].w * acc[q].w;
    }
    prt[r][s] = p;
  }
  __syncthreads();   // WsT/WsT2/hs/prt all visible
  if (s == 0) sqno[n] = ((prt[r][0] + prt[r][1]) + prt[r][2]) + prt[r][3];

  const int o = t & 63;
  for (int g4 = 0; g4 < 64; g4 += 4) {
    const int g = g4 + (t >> 6);
    float uu = 0.f, vv = 0.f;
    #pragma unroll
    for (int f4 = 0; f4 < 64; f4 += 4) {
      float4 hv = *(const float4*)&hs[g][f4];
      float4 wa = *(const float4*)&WsT [o * LWT + f4];
      float4 wb = *(const float4*)&WsT2[o * LWT + f4];
      uu += hv.x * wa.x; vv += hv.x * wb.x;
      uu += hv.y * wa.y; vv += hv.y * wb.y;
      uu += hv.z * wa.z; vv += hv.z * wb.z;
      uu += hv.w * wa.w; vv += hv.w * wb.w;
    }
    Uo[(size_t)(n0 + g) * 64 + o] = uu;
    Vo[(size_t)(n0 + g) * 64 + o] = vv;
  }
}

// ---------------- MFMA bf16x2 (hi/lo, 3-term) GEMM, 128x128 tile ----------------
// MODE0: epilogue staged through LDS -> fully coalesced b128 stores.
template <int MODE>
__global__ __launch_bounds__(256) void mfma_gemm(const short* __restrict__ AH,
                                                 const short* __restrict__ AL,
                                                 const short* __restrict__ BH,
                                                 const short* __restrict__ BL,
                                                 const float* __restrict__ bias,
                                                 short* __restrict__ outH,
                                                 short* __restrict__ outL,
                                                 unsigned* __restrict__ pooled,
                                                 int Msl, int zc, int g0) {
  constexpr int Kdim = (MODE == 0) ? 384 : 512;
  __shared__ __align__(16) short pool4[4 * 128 * 40];   // AHs|ALs|BHs|BLs; epilogue zs
  short (*AHs)[40] = (short(*)[40])(pool4);
  short (*ALs)[40] = (short(*)[40])(pool4 + 5120);
  short (*BHs)[40] = (short(*)[40])(pool4 + 10240);
  short (*BLs)[40] = (short(*)[40])(pool4 + 15360);
  __shared__ float red[8][132];
  const int t = threadIdx.x;
  const int m0 = blockIdx.y * 128, n0 = blockIdx.x * 128;
  const int w = t >> 6, l = t & 63;
  const int q = w >> 1, p = w & 1, rl = l & 15, kb = l >> 4;
  const int srow = t >> 1, sc = (t & 1) * 16;

  f32x4 acc[4][4];
  #pragma unroll
  for (int m = 0; m < 4; ++m)
    #pragma unroll
    for (int n = 0; n < 4; ++n) acc[m][n] = (f32x4){0.f, 0.f, 0.f, 0.f};

  for (int k0 = 0; k0 < Kdim; k0 += 32) {
    size_t aoff, boff;
    if constexpr (MODE == 0)
      aoff = ((size_t)(k0 >> 6) * Msl + zc + m0 + srow) * 64 + (k0 & 63) + sc;
    else
      aoff = (size_t)(m0 + srow) * 512 + k0 + sc;
    boff = (size_t)(n0 + srow) * Kdim + k0 + sc;
    uint4 ga0 = *(const uint4*)(AH + aoff);
    uint4 ga1 = *(const uint4*)(AH + aoff + 8);
    uint4 gl0 = *(const uint4*)(AL + aoff);
    uint4 gl1 = *(const uint4*)(AL + aoff + 8);
    uint4 gb0 = *(const uint4*)(BH + boff);
    uint4 gb1 = *(const uint4*)(BH + boff + 8);
    uint4 gc0 = *(const uint4*)(BL + boff);
    uint4 gc1 = *(const uint4*)(BL + boff + 8);
    __syncthreads();
    *(uint4*)&AHs[srow][sc]     = ga0;
    *(uint4*)&AHs[srow][sc + 8] = ga1;
    *(uint4*)&ALs[srow][sc]     = gl0;
    *(uint4*)&ALs[srow][sc + 8] = gl1;
    *(uint4*)&BHs[srow][sc]     = gb0;
    *(uint4*)&BHs[srow][sc + 8] = gb1;
    *(uint4*)&BLs[srow][sc]     = gc0;
    *(uint4*)&BLs[srow][sc + 8] = gc1;
    __syncthreads();

    s16x8 aH[4], aL[4], bH[4], bL[4];
    #pragma unroll
    for (int m = 0; m < 4; ++m) {
      aH[m] = *(const s16x8*)&AHs[q * 64 + m * 16 + rl][kb * 8];
      aL[m] = *(const s16x8*)&ALs[q * 64 + m * 16 + rl][kb * 8];
    }
    #pragma unroll
    for (int n = 0; n < 4; ++n) {
      bH[n] = *(const s16x8*)&BHs[p * 64 + n * 16 + rl][kb * 8];
      bL[n] = *(const s16x8*)&BLs[p * 64 + n * 16 + rl][kb * 8];
    }
    #pragma unroll
    for (int m = 0; m < 4; ++m)
      #pragma unroll
      for (int n = 0; n < 4; ++n) {
        acc[m][n] = mfma16(aH[m], bH[n], acc[m][n]);
        acc[m][n] = mfma16(aH[m], bL[n], acc[m][n]);
        acc[m][n] = mfma16(aL[m], bH[n], acc[m][n]);
      }
  }

  if constexpr (MODE == 0) {
    constexpr int LZS = 136;  // shorts; rows 272B (16B-aligned)
    short* zs = pool4;        // 128*136*2 = 34816 B <= 40960 B
    __syncthreads();          // all LDS reads of K-loop done
    // ---- pass H: stage hv, coalesced store ----
    #pragma unroll
    for (int n = 0; n < 4; ++n) {
      const int lcol = p * 64 + n * 16 + rl;
      const float bv = bias[n0 + lcol];
      #pragma unroll
      for (int m = 0; m < 4; ++m)
        #pragma unroll
        for (int rr = 0; rr < 4; ++rr) {
          int lrow = q * 64 + m * 16 + kb * 4 + rr;
          float v = lrelu(acc[m][n][rr] + bv);
          zs[lrow * LZS + lcol] = (short)f2bf(v);
        }
    }
    __syncthreads();
    {
      const int lr = t >> 4, ck = (t & 15) * 8;
      #pragma unroll
      for (int ps2 = 0; ps2 < 8; ++ps2) {
        int lrow = ps2 * 16 + lr;
        *(uint4*)&outH[(size_t)(m0 + lrow) * 512 + n0 + ck] =
            *(const uint4*)&zs[lrow * LZS + ck];
      }
    }
    __syncthreads();
    // ---- pass L: stage lv (recomputed from live acc), coalesced store ----
    #pragma unroll
    for (int n = 0; n < 4; ++n) {
      const int lcol = p * 64 + n * 16 + rl;
      const float bv = bias[n0 + lcol];
      #pragma unroll
      for (int m = 0; m < 4; ++m)
        #pragma unroll
        for (int rr = 0; rr < 4; ++rr) {
          int lrow = q * 64 + m * 16 + kb * 4 + rr;
          float v = lrelu(acc[m][n][rr] + bv);
          unsigned short hv = f2bf(v);
          zs[lrow * LZS + lcol] = (short)f2bf(v - bf2f(hv));
        }
    }
    __syncthreads();
    {
      const int lr = t >> 4, ck = (t & 15) * 8;
      #pragma unroll
      for (int ps2 = 0; ps2 < 8; ++ps2) {
        int lrow = ps2 * 16 + lr;
        *(uint4*)&outL[(size_t)(m0 + lrow) * 512 + n0 + ck] =
            *(const uint4*)&zs[lrow * LZS + ck];
      }
    }
  } else {
    #pragma unroll
    for (int n = 0; n < 4; ++n) {
      float cm = acc[0][n][0];
      #pragma unroll
      for (int m = 0; m < 4; ++m)
        #pragma unroll
        for (int rr = 0; rr < 4; ++rr) cm = fmaxf(cm, acc[m][n][rr]);
      red[q * 4 + kb][p * 64 + n * 16 + rl] = cm;
    }
    __syncthreads();
    if (t < 128) {
      float m = red[0][t];
      #pragma unroll
      for (int rr = 1; rr < 8; ++rr) m = fmaxf(m, red[rr][t]);
      m += bias[n0 + t];
      int g = g0 + ((zc + m0) >> 10);
      atomicMax(&pooled[(size_t)g * 512 + n0 + t], encf(m));
    }
  }
}

// ---------------- head ----------------
__global__ __launch_bounds__(256) void head_kernel(const unsigned* __restrict__ pooled,
                                                   const float* __restrict__ Wm1,
                                                   const float* __restrict__ bm1,
                                                   const float* __restrict__ Wm2,
                                                   const float* __restrict__ bm2,
                                                   float* __restrict__ out) {
  __shared__ float ps[512];
  __shared__ float hs[256];
  int b = blockIdx.x;
  int t = threadIdx.x;
  for (int l = t; l < 512; l += 256) ps[l] = decf(pooled[(size_t)b * 512 + l]);
  __syncthreads();
  float acc = bm1[t];
  for (int f = 0; f < 512; ++f) acc += ps[f] * Wm1[f * 256 + t];
  hs[t] = lrelu(acc);
  __syncthreads();
  if (t < 3) {
    float y = bm2[t];
    for (int f = 0; f < 256; ++f) y += hs[f] * Wm2[f * 3 + t];
    out[b * 3 + t] = y;
  }
}

static inline size_t al256(size_t v) { return (v + 255) & ~(size_t)255; }

extern "C" void kernel_launch(void* const* d_in, const int* in_sizes, int n_in,
                              void* d_out, int out_size, void* d_ws, size_t ws_size,
                              hipStream_t stream) {
  (void)in_sizes; (void)n_in; (void)out_size;
  const float* x    = (const float*)d_in[0];
  const float* pos  = (const float*)d_in[1];
  const float* tq   = (const float*)d_in[2];
  // d_in[3] = batch (uniform & sorted; unused)
  const float* W1   = (const float*)d_in[4];
  const float* b1   = (const float*)d_in[5];
  const float* W2   = (const float*)d_in[6];
  const float* b2   = (const float*)d_in[7];
  const float* Wl1a = (const float*)d_in[8];
  const float* bl1a = (const float*)d_in[9];
  const float* Wl1b = (const float*)d_in[10];
  const float* bl1b = (const float*)d_in[11];
  const float* Wm1  = (const float*)d_in[12];
  const float* bm1  = (const float*)d_in[13];
  const float* Wm2  = (const float*)d_in[14];
  const float* bm2  = (const float*)d_in[15];
  float* out = (float*)d_out;

  // ---- pick largest graph-chunk G whose workspace fits ----
  auto calc = [&](int G, size_t& hHB, size_t& uvB, size_t& uvzB) -> size_t {
    size_t M = (size_t)G * Nn;
    hHB = al256(M * 384 * 2);                 // hH (and hL): 6 slots [M][64] bf16
    uvB = al256(M * 64 * 4);                  // each of Ua,Va,Ub,Vb
    size_t Mz = M < 16384 ? M : 16384;
    size_t zB = 2 * al256(Mz * 512 * 2);      // zH+zL (alias U/V region)
    uvzB = (4 * uvB > zB) ? 4 * uvB : zB;
    size_t convS = al256(M * 5 * 4) + al256(M * 4) + al256(M * Kk * 4);
    size_t wB = 2 * al256((size_t)512 * 384 * 2) + 2 * al256((size_t)512 * 512 * 2);
    return 2 * hHB + uvzB + convS + al256((size_t)Bg * 512 * 4) + wB + 1024;
  };
  int G = 64;
  size_t hHB = 0, uvB = 0, uvzB = 0;
  while (G > 1 && calc(G, hHB, uvB, uvzB) > ws_size) G >>= 1;
  calc(G, hHB, uvB, uvzB);
  const int M = G * Nn;
  const int Mz = M < 16384 ? M : 16384;

  char* w = (char*)d_ws;
  short* hH = (short*)w;
  short* hL = (short*)(w + hHB);
  char*  uvz = w + 2 * hHB;
  float* Ua = (float*)uvz;
  float* Va = (float*)(uvz + uvB);
  float* Ub = (float*)(uvz + 2 * uvB);
  float* Vb = (float*)(uvz + 3 * uvB);
  short* zH = (short*)uvz;                                  // MLP aliases U/V region
  short* zL = (short*)(uvz + al256((size_t)Mz * 512 * 2));
  char*  conv = uvz + uvzB;
  float* xx  = (float*)conv;
  float* sqn = (float*)(conv + al256((size_t)M * 5 * 4));
  int*   idx = (int*)((char*)sqn + al256((size_t)M * 4));
  unsigned* pooled = (unsigned*)((char*)idx + al256((size_t)M * Kk * 4));
  short* WHa = (short*)((char*)pooled + al256((size_t)Bg * 512 * 4));
  short* WLa = WHa + (size_t)512 * 384;
  short* WHb = (short*)((char*)WHa + 2 * al256((size_t)512 * 384 * 2));
  short* WLb = WHb + (size_t)512 * 512;

  wprep<384><<<(384 * 512) / 256, 256, 0, stream>>>(Wl1a, WHa, WLa);
  wprep<512><<<(512 * 512) / 256, 256, 0, stream>>>(Wl1b, WHb, WLb);
  pooled_init<<<(Bg * 512) / 256, 256, 0, stream>>>(pooled);

  for (int g0 = 0; g0 < Bg; g0 += G) {
    build_xx<<<M / 256, 256, 0, stream>>>(x, pos, tq, xx, sqn, g0 * Nn);

    // conv1 (F=5, W1) -> slot 0; fused uv(conv2)+sq
    uv_kernel<5><<<M / 16, 256, 0, stream>>>(xx, W1, Ua, Va);
    knn_kernel<5><<<dim3(Nn / 64, G), 256, 0, stream>>>(xx, sqn, idx);

    float *Ui = Ua, *Vi = Va, *Uo = Ub, *Vo = Vb;
    aggF_kernel<true><<<M / 64, 256, 0, stream>>>(Ui, Vi, idx, b1, hH, hL,
                                                  W2, Uo, Vo, sqn);
    { float* tp = Ui; Ui = Uo; Uo = tp; tp = Vi; Vi = Vo; Vo = tp; }

    // conv2..6 -> slots 1..5
    for (int c = 1; c < 6; ++c) {
      knn64_mfma<<<dim3(Nn / 64, G), 256, 0, stream>>>(hH + (size_t)(c - 1) * M * 64,
                                                       hL + (size_t)(c - 1) * M * 64,
                                                       sqn, idx);
      if (c < 5) {
        aggF_kernel<true><<<M / 64, 256, 0, stream>>>(Ui, Vi, idx, b2,
                                                      hH + (size_t)c * M * 64,
                                                      hL + (size_t)c * M * 64,
                                                      W2, Uo, Vo, sqn);
        { float* tp = Ui; Ui = Uo; Uo = tp; tp = Vi; Vi = Vo; Vo = tp; }
      } else {
        aggF_kernel<false><<<M / 64, 256, 0, stream>>>(Ui, Vi, idx, b2,
                                                       hH + (size_t)5 * M * 64,
                                                       hL + (size_t)5 * M * 64,
                                                       nullptr, nullptr, nullptr, nullptr);
      }
    }

    // MLP over this chunk's rows, z-chunked
    for (int zc = 0; zc < M; zc += Mz) {
      mfma_gemm<0><<<dim3(4, Mz / 128), 256, 0, stream>>>(hH, hL, WHa, WLa, bl1a,
                                                          zH, zL, nullptr, M, zc, 0);
      mfma_gemm<1><<<dim3(4, Mz / 128), 256, 0, stream>>>(zH, zL, WHb, WLb, bl1b,
                                                          nullptr, nullptr, pooled, Mz, zc, g0);
    }
  }

  head_kernel<<<Bg, 256, 0, stream>>>(pooled, Wm1, bm1, Wm2, bm2, out);
}